// Round 11
// baseline (873.400 us; speedup 1.0000x reference)
//
#include <hip/hip_runtime.h>
#include <stdint.h>

typedef short bf16x8 __attribute__((ext_vector_type(8)));
typedef float f32x4 __attribute__((ext_vector_type(4)));

__device__ __forceinline__ unsigned short f2bf(float f) {
  union { float f; unsigned int i; } v; v.f = f;
  unsigned int r = v.i + 0x7FFF + ((v.i >> 16) & 1);
  return (unsigned short)(r >> 16);
}
__device__ __forceinline__ void gload_lds16(const void* g, void* l) {
  __builtin_amdgcn_global_load_lds(
      (const __attribute__((address_space(1))) unsigned int*)g,
      (__attribute__((address_space(3))) unsigned int*)l,
      16, 0, 0);
}

// ---------------- convert f32 weights -> bf16 (Whh0, Wih1, Whh1, Wout) ----------------
__global__ __launch_bounds__(256) void k_cvt(const float* __restrict__ s0, const float* __restrict__ s1,
                                             const float* __restrict__ s2, const float* __restrict__ s3,
                                             unsigned short* __restrict__ d0, unsigned short* __restrict__ d1,
                                             unsigned short* __restrict__ d2, unsigned short* __restrict__ d3) {
  int j = blockIdx.x * 256 + threadIdx.x;   // 6656*256 = 1,703,936 vec8 jobs exactly
  const float* s; unsigned short* d; int o;
  if (j < 524288)       { s = s0; d = d0; o = j; }
  else if (j < 1048576) { s = s1; d = d1; o = j - 524288; }
  else if (j < 1572864) { s = s2; d = d2; o = j - 1048576; }
  else                  { s = s3; d = d3; o = j - 1572864; }
  size_t off = (size_t)o * 8;
  f32x4 v0 = *(const f32x4*)(s + off);
  f32x4 v1 = *(const f32x4*)(s + off + 4);
  bf16x8 r;
#pragma unroll
  for (int k = 0; k < 4; k++) { r[k] = (short)f2bf(v0[k]); r[4 + k] = (short)f2bf(v1[k]); }
  *(bf16x8*)(d + off) = r;
}

// ---------------- prep: embedding gather (f32) + zero state + zero flags ----------------
__global__ __launch_bounds__(256) void k_prep(const int* __restrict__ ys,
                                              const float* __restrict__ embed,
                                              float* __restrict__ eys,
                                              float* __restrict__ h0h, float* __restrict__ h1h,
                                              int* __restrict__ flags) {
  int idx = blockIdx.x * 256 + threadIdx.x;   // 16384 threads
  int row = idx >> 6;
  int e = (idx & 63) * 8;
  int y = ys[row];
  f32x4 v0 = {0.f, 0.f, 0.f, 0.f}, v1 = {0.f, 0.f, 0.f, 0.f};
  if (y != 0) {
    v0 = *(const f32x4*)(embed + (size_t)y * 512 + e);
    v1 = *(const f32x4*)(embed + (size_t)y * 512 + e + 4);
  }
  *(f32x4*)(eys + (size_t)row * 512 + e) = v0;
  *(f32x4*)(eys + (size_t)row * 512 + e + 4) = v1;
  if (idx < 4096) { h0h[idx] = 0.f; h1h[idx] = 0.f; }
  if (idx < 64) flags[idx] = 0;
}

// -------- generic small GEMM: C(f32 MxN) = A(f32 MxK) @ W(f32 NxK)^T + b1 + b2 --------
__global__ __launch_bounds__(256) void k_gemm_bias(const float* __restrict__ A,
                                                   const float* __restrict__ W,
                                                   const float* __restrict__ b1,
                                                   const float* __restrict__ b2,
                                                   float* __restrict__ C,
                                                   int M, int N, int K) {
  __shared__ unsigned short Als[64][40];
  __shared__ unsigned short Wls[64][40];
  int tid = threadIdx.x;
  int lane = tid & 63, wid = tid >> 6;
  int mtiles = M >> 6;
  int mt = blockIdx.x % mtiles, nt = blockIdx.x / mtiles;
  int srow = tid >> 2, sseg = tid & 3;
  f32x4 acc[4];
#pragma unroll
  for (int nf = 0; nf < 4; nf++) acc[nf] = (f32x4){0.f, 0.f, 0.f, 0.f};

  for (int kc = 0; kc < K; kc += 32) {
    const float* ap = A + (size_t)(mt * 64 + srow) * K + kc + sseg * 8;
    const float* wp = W + (size_t)(nt * 64 + srow) * K + kc + sseg * 8;
    f32x4 a0 = *(const f32x4*)ap, a1 = *(const f32x4*)(ap + 4);
    f32x4 w0 = *(const f32x4*)wp, w1 = *(const f32x4*)(wp + 4);
    bf16x8 av, wv;
#pragma unroll
    for (int k = 0; k < 4; k++) {
      av[k] = (short)f2bf(a0[k]); av[4 + k] = (short)f2bf(a1[k]);
      wv[k] = (short)f2bf(w0[k]); wv[4 + k] = (short)f2bf(w1[k]);
    }
    __syncthreads();
    *(bf16x8*)(&Als[srow][sseg * 8]) = av;
    *(bf16x8*)(&Wls[srow][sseg * 8]) = wv;
    __syncthreads();
    bf16x8 af = *(const bf16x8*)(&Als[wid * 16 + (lane & 15)][(lane >> 4) * 8]);
#pragma unroll
    for (int nf = 0; nf < 4; nf++) {
      bf16x8 bf = *(const bf16x8*)(&Wls[nf * 16 + (lane & 15)][(lane >> 4) * 8]);
      acc[nf] = __builtin_amdgcn_mfma_f32_16x16x32_bf16(af, bf, acc[nf], 0, 0, 0);
    }
  }
  int rloc = (lane >> 4) * 4;
  int col0 = lane & 15;
#pragma unroll
  for (int nf = 0; nf < 4; nf++) {
    int n = nt * 64 + nf * 16 + col0;
    float bias = 0.f;
    if (b1) bias += b1[n];
    if (b2) bias += b2[n];
#pragma unroll
    for (int r = 0; r < 4; r++) {
      int m = mt * 64 + wid * 16 + rloc + r;
      C[(size_t)m * N + n] = acc[nf][r] + bias;
    }
  }
}

// ---------------- fused LSTM v3: 64 merged blocks, single sync domain (unchanged) ------
__global__ __launch_bounds__(512, 2) void k_lstm_fused(
    const float* __restrict__ X0,            // (B,U,4096)  eys@Wih0^T + bih0 + bhh0
    float* __restrict__ h0h,                 // (65,B,1024)
    float* __restrict__ h1h,                 // (65,B,1024)
    float* __restrict__ hdec,                // (B,U,1024) f32
    const unsigned short* __restrict__ W_hh0,
    const unsigned short* __restrict__ W_ih1,
    const unsigned short* __restrict__ W_hh1,
    const float* __restrict__ b_ih1,
    const float* __restrict__ b_hh1,
    int* __restrict__ flags) {               // 64 flags
  __shared__ unsigned short X_lds[4][2064];  // 4 batches x 2048 k (+16 pad)
  __shared__ float red0[8][4][16][4];        // 8 KB
  __shared__ float red1[8][4][16][4];        // 8 KB
  __shared__ float gsum[2][4][16][4];        // 2 KB
  int tid = threadIdx.x;
  int lane = tid & 63, w = tid >> 6;
  int bid = blockIdx.x;                      // 0..63
  int base = bid * 16;

  bf16x8 wf0[4][4];    // [gate][ks], layer0: K=128 per wave
  bf16x8 wf1[4][8];    // layer1: K=256 per wave (k<1024 -> Wih1, else Whh1)
  int ch = lane & 15;
  int kb0 = w * 128, kb1 = w * 256;
  int klo = (lane >> 4) << 3;
#pragma unroll
  for (int nt = 0; nt < 4; nt++) {
    int grow = nt * 1024 + base + ch;
#pragma unroll
    for (int ks = 0; ks < 4; ks++)
      wf0[nt][ks] = *(const bf16x8*)(W_hh0 + (size_t)grow * 1024 + kb0 + ks * 32 + klo);
#pragma unroll
    for (int ks = 0; ks < 8; ks++) {
      int k = kb1 + ks * 32 + klo;
      const unsigned short* src = (k < 1024) ? (W_ih1 + (size_t)grow * 1024 + k)
                                             : (W_hh1 + (size_t)grow * 1024 + (k - 1024));
      wf1[nt][ks] = *(const bf16x8*)src;
    }
  }

  float creg = 0.f;
  float bs0 = 0.f, bs1 = 0.f, bs2 = 0.f, bs3 = 0.f;
  int gch = (tid & 63) >> 2, gb = tid & 3;
  if (tid >= 64 && tid < 128) {
    int c = base + gch;
    bs0 = b_ih1[c] + b_hh1[c];
    bs1 = b_ih1[1024 + c] + b_hh1[1024 + c];
    bs2 = b_ih1[2048 + c] + b_hh1[2048 + c];
    bs3 = b_ih1[3072 + c] + b_hh1[3072 + c];
  }

  int ar = ch & 3;
  for (int p = 0; p <= 64; p++) {
    bool act0 = (p < 64), act1 = (p >= 1);
    if (p > 0) {
      if (w == 0) {
        while (true) {
          int f = __hip_atomic_load(&flags[lane], __ATOMIC_RELAXED, __HIP_MEMORY_SCOPE_AGENT);
          if (__all(f >= p)) break;
          __builtin_amdgcn_s_sleep(1);
        }
      }
      __syncthreads();
    }
    {
      int b = tid >> 7, k0 = (tid & 127) * 16;
      if (k0 < 1024 || act1) {
        const float* fsrc = (k0 < 1024) ? (h0h + (size_t)p * 4096 + b * 1024 + k0)
                                        : (h1h + (size_t)(p - 1) * 4096 + b * 1024 + (k0 - 1024));
        const unsigned long long* s8 = (const unsigned long long*)fsrc;
        unsigned long long v[8];
#pragma unroll
        for (int i = 0; i < 8; i++)
          v[i] = __hip_atomic_load(s8 + i, __ATOMIC_RELAXED, __HIP_MEMORY_SCOPE_AGENT);
        bf16x8 r0, r1;
#pragma unroll
        for (int i = 0; i < 4; i++) {
          union { unsigned long long u; float f[2]; } cv; cv.u = v[i];
          r0[2 * i] = (short)f2bf(cv.f[0]); r0[2 * i + 1] = (short)f2bf(cv.f[1]);
        }
#pragma unroll
        for (int i = 0; i < 4; i++) {
          union { unsigned long long u; float f[2]; } cv; cv.u = v[4 + i];
          r1[2 * i] = (short)f2bf(cv.f[0]); r1[2 * i + 1] = (short)f2bf(cv.f[1]);
        }
        *(bf16x8*)&X_lds[b][k0] = r0;
        *(bf16x8*)&X_lds[b][k0 + 8] = r1;
      }
    }
    __syncthreads();

    if (act0) {
      f32x4 acc[4];
#pragma unroll
      for (int nt = 0; nt < 4; nt++) acc[nt] = (f32x4){0.f, 0.f, 0.f, 0.f};
#pragma unroll
      for (int ks = 0; ks < 4; ks++) {
        bf16x8 a = *(const bf16x8*)&X_lds[ar][kb0 + ks * 32 + klo];
#pragma unroll
        for (int nt = 0; nt < 4; nt++)
          acc[nt] = __builtin_amdgcn_mfma_f32_16x16x32_bf16(a, wf0[nt][ks], acc[nt], 0, 0, 0);
      }
      if (lane < 16) {
#pragma unroll
        for (int nt = 0; nt < 4; nt++) *(f32x4*)&red0[w][nt][lane][0] = acc[nt];
      }
    }
    if (act1) {
      f32x4 acc[4];
#pragma unroll
      for (int nt = 0; nt < 4; nt++) acc[nt] = (f32x4){0.f, 0.f, 0.f, 0.f};
#pragma unroll
      for (int ks = 0; ks < 8; ks++) {
        bf16x8 a = *(const bf16x8*)&X_lds[ar][kb1 + ks * 32 + klo];
#pragma unroll
        for (int nt = 0; nt < 4; nt++)
          acc[nt] = __builtin_amdgcn_mfma_f32_16x16x32_bf16(a, wf1[nt][ks], acc[nt], 0, 0, 0);
      }
      if (lane < 16) {
#pragma unroll
        for (int nt = 0; nt < 4; nt++) *(f32x4*)&red1[w][nt][lane][0] = acc[nt];
      }
    }
    __syncthreads();
    {
      int layer = tid >> 8, nt = (tid >> 6) & 3, cc = (tid >> 2) & 15, q = tid & 3;
      const float (*rp)[4][16][4] = layer ? red1 : red0;
      float s = 0.f;
#pragma unroll
      for (int w8 = 0; w8 < 8; w8++) s += rp[w8][nt][cc][q];
      gsum[layer][nt][cc][q] = s;
    }
    __syncthreads();
    if (tid < 128) {
      int layer = tid >> 6;
      bool act = layer ? act1 : act0;
      if (act) {
        float gi = gsum[layer][0][gch][gb], gf = gsum[layer][1][gch][gb];
        float gg = gsum[layer][2][gch][gb], go = gsum[layer][3][gch][gb];
        if (layer == 0) {
          const float* x0p = X0 + ((size_t)(gb * 64 + p)) * 4096 + base + gch;
          gi += x0p[0]; gf += x0p[1024]; gg += x0p[2048]; go += x0p[3072];
        } else {
          gi += bs0; gf += bs1; gg += bs2; go += bs3;
        }
        float ii = 1.f / (1.f + __expf(-gi));
        float ff = 1.f / (1.f + __expf(-gf));
        float oo = 1.f / (1.f + __expf(-go));
        float cn = ff * creg + ii * tanhf(gg);
        creg = cn;
        float hn = oo * tanhf(cn);
        if (layer == 0) {
          __hip_atomic_store(&h0h[(size_t)(p + 1) * 4096 + gb * 1024 + base + gch], hn,
                             __ATOMIC_RELAXED, __HIP_MEMORY_SCOPE_AGENT);
        } else {
          __hip_atomic_store(&h1h[(size_t)p * 4096 + gb * 1024 + base + gch], hn,
                             __ATOMIC_RELAXED, __HIP_MEMORY_SCOPE_AGENT);
          hdec[((size_t)(gb * 64 + (p - 1))) * 1024 + base + gch] = hn;
        }
      }
    }
    asm volatile("s_waitcnt vmcnt(0)" ::: "memory");
    __syncthreads();
    if (tid == 0 && p < 64)
      __hip_atomic_store(&flags[bid], p + 1, __ATOMIC_RELAXED, __HIP_MEMORY_SCOPE_AGENT);
  }
}

// ---------------- joint v4: barrier-free self-paced waves -----------------------------
// 512 blocks (one (b,t) each, M=64 u-rows) x 512 threads, 1 block/CU.
// Waves: 2 m-groups (32 rows) x 4 n-slices (32 of the 128 chunk rows). Each wave owns
// 4 private 4KB LDS buffers, stages its own B-slice (gload_lds), counts its own vmcnt.
// NO barriers in the main loop. Depth-3 pipeline: vmcnt(8) = chunk c's 4 loads retired.
__global__ __launch_bounds__(512, 2) void k_joint(const float* __restrict__ encp,   // (B,T,512)
                                                  const float* __restrict__ decp,   // (B,U,512)
                                                  const unsigned short* __restrict__ Wout, // (2048,512) bf16
                                                  const float* __restrict__ bout,   // (2048) f32
                                                  float* __restrict__ out) {        // (B,T,U,2048) f32
  __shared__ unsigned short Wls[8][4][2048]; // 8 waves x 4 bufs x 4KB = 128KB
  int tid = threadIdx.x;
  int lane = tid & 63, wid = tid >> 6;       // 8 waves
  int mg = wid >> 2;                         // m-group: rows mg*32..mg*32+31
  int ws = wid & 3;                          // n-slice: chunk rows ws*32..ws*32+31
  int bidx = blockIdx.x;                     // 512 = (b,t)
  size_t rowbase = (size_t)bidx * 64;        // out row = (b*128+t)*64 + u
  int b = bidx >> 7, tloc = bidx & 127;

#define STAGE(cg)                                                              \
  {                                                                            \
    int nn0_ = (((cg) >> 3) << 7) + ws * 32;                                   \
    int kb_ = ((cg) & 7) * 64;                                                 \
    unsigned short* dst_ = &Wls[wid][(cg) & 3][0];                             \
    _Pragma("unroll")                                                          \
    for (int q_ = 0; q_ < 4; q_++) {                                           \
      int idx_ = q_ * 64 + lane;                                               \
      int n_ = idx_ >> 3, sl_ = idx_ & 7;                                      \
      int ss_ = sl_ ^ (n_ & 7);                                                \
      gload_lds16(Wout + (size_t)(nn0_ + n_) * 512 + kb_ + ss_ * 8, dst_ + idx_ * 8); \
    }                                                                          \
  }

  // ---- prologue: 3 chunks in flight ----
  STAGE(0)
  STAGE(1)
  STAGE(2)

  // ---- bias preload: 32 regs (16 n-tiles x 2 nf) ----
  float bb[16][2];
#pragma unroll
  for (int t16 = 0; t16 < 16; t16++)
#pragma unroll
    for (int nf = 0; nf < 2; nf++)
      bb[t16][nf] = bout[t16 * 128 + ws * 32 + nf * 16 + (lane & 15)];

  // ---- A panel: 2 m-frags x 16 k-frags (128 VGPR) ----
  bf16x8 afr[32];
  {
    const float* ep = encp + ((size_t)(b * 128 + tloc)) * 512;
#pragma unroll
    for (int mf = 0; mf < 2; mf++) {
      int u = mg * 32 + mf * 16 + (lane & 15);
      const float* dp = decp + ((size_t)(b * 64 + u)) * 512;
#pragma unroll
      for (int kf = 0; kf < 16; kf++) {
        int k0 = kf * 32 + ((lane >> 4) << 3);
        bf16x8 v;
#pragma unroll
        for (int j = 0; j < 8; j++) {
          float x = ep[k0 + j] + dp[k0 + j];
          float e = __expf(x + x);
          v[j] = (short)f2bf(1.f - 2.f / (e + 1.f));
        }
        afr[mf * 16 + kf] = v;
      }
    }
  }

  f32x4 acc[2][2];
#pragma unroll
  for (int mf = 0; mf < 2; mf++)
#pragma unroll
    for (int nf = 0; nf < 2; nf++) acc[mf][nf] = (f32x4){0.f, 0.f, 0.f, 0.f};

  // ---- main loop: 128 chunks, self-paced, NO barriers ----
  for (int c = 0; c < 128; c++) {
    asm volatile("s_waitcnt vmcnt(8)" ::: "memory");   // own chunk-c loads retired
    const unsigned short* Wb = &Wls[wid][c & 3][0];
    int kc = c & 7;
#pragma unroll
    for (int ks = 0; ks < 2; ks++) {
      bf16x8 bfr[2];
#pragma unroll
      for (int nf = 0; nf < 2; nf++) {
        int nl = nf * 16 + (lane & 15);
        int slot = ks * 4 + (lane >> 4);
        int phys = slot ^ (nl & 7);
        bfr[nf] = *(const bf16x8*)(Wb + nl * 64 + phys * 8);
      }
      int kf = kc * 2 + ks;
#pragma unroll
      for (int mf = 0; mf < 2; mf++)
#pragma unroll
        for (int nf = 0; nf < 2; nf++)
          acc[mf][nf] = __builtin_amdgcn_mfma_f32_16x16x32_bf16(afr[mf * 16 + kf], bfr[nf],
                                                                acc[mf][nf], 0, 0, 0);
    }
    if (kc == 7) {                      // epilogue for this n-tile: direct NT stores
      int t16 = c >> 3;
      int n0 = t16 << 7;
#pragma unroll
      for (int mf = 0; mf < 2; mf++) {
        int rb = mg * 32 + mf * 16 + ((lane >> 4) << 2);
#pragma unroll
        for (int nf = 0; nf < 2; nf++) {
          int o = n0 + ws * 32 + nf * 16 + (lane & 15);
          float bias = bb[t16][nf];
#pragma unroll
          for (int q = 0; q < 4; q++)
            __builtin_nontemporal_store(acc[mf][nf][q] + bias,
                                        &out[(rowbase + rb + q) * 2048 + o]);
          acc[mf][nf] = (f32x4){0.f, 0.f, 0.f, 0.f};
        }
      }
    }
    if (c < 125) STAGE(c + 3)
  }
#undef STAGE
}

// ---------------- launch ----------------
extern "C" void kernel_launch(void* const* d_in, const int* in_sizes, int n_in,
                              void* d_out, int out_size, void* d_ws, size_t ws_size,
                              hipStream_t stream) {
  const float* hs   = (const float*)d_in[0];
  const int*   ys   = (const int*)d_in[1];
  const float* emb  = (const float*)d_in[2];
  const float* Wih0 = (const float*)d_in[3];
  const float* Whh0 = (const float*)d_in[4];
  const float* bih0 = (const float*)d_in[5];
  const float* bhh0 = (const float*)d_in[6];
  const float* Wih1 = (const float*)d_in[7];
  const float* Whh1 = (const float*)d_in[8];
  const float* bih1 = (const float*)d_in[9];
  const float* bhh1 = (const float*)d_in[10];
  const float* Wenc = (const float*)d_in[11];
  const float* benc = (const float*)d_in[12];
  const float* Wdec = (const float*)d_in[13];
  const float* Wout = (const float*)d_in[14];
  const float* bout = (const float*)d_in[15];

  char* ws = (char*)d_ws;
  float*          eys   = (float*)(ws + 0);            // 256x512 f32        = 524,288
  float*          X0    = (float*)(ws + 524288);       // 256x4096 f32       = 4,194,304
  float*          encp  = (float*)(ws + 4718592);      // 512x512 f32        = 1,048,576
  float*          decp  = (float*)(ws + 5767168);      // 256x512 f32        = 524,288
  float*          h0h   = (float*)(ws + 6291456);      // 65x4096 f32        = 1,064,960
  float*          h1h   = (float*)(ws + 7356416);      // 65x4096 f32        = 1,064,960
  float*          hdec  = (float*)(ws + 8421376);      // 256x1024 f32       = 1,048,576
  int*            flags = (int*)(ws + 9469952);        // 64 ints
  unsigned short* Whh0b = (unsigned short*)(ws + 9502720);   // 4M bf16      = 8,388,608
  unsigned short* Wih1b = (unsigned short*)(ws + 17891328);  // 4M bf16      = 8,388,608
  unsigned short* Whh1b = (unsigned short*)(ws + 26279936);  // 4M bf16      = 8,388,608
  unsigned short* Woutb = (unsigned short*)(ws + 34668544);  // 1M bf16      = 2,097,152
  float*          out   = (float*)d_out;                     // total ws = 36,765,696 B

  // weight conversion (bf16 for LSTM recurrent mats + Wout for global_load_lds)
  k_cvt<<<6656, 256, 0, stream>>>(Whh0, Wih1, Whh1, Wout, Whh0b, Wih1b, Whh1b, Woutb);
  k_prep<<<64, 256, 0, stream>>>(ys, emb, eys, h0h, h1h, flags);
  // X0 = eys @ Wih0^T + bih0 + bhh0   (M=256, N=4096, K=512)
  k_gemm_bias<<<256, 256, 0, stream>>>(eys, Wih0, bih0, bhh0, X0, 256, 4096, 512);
  // encp = hs @ Wenc^T + benc         (M=512, N=512, K=512)
  k_gemm_bias<<<64, 256, 0, stream>>>(hs, Wenc, benc, nullptr, encp, 512, 512, 512);
  // fused LSTM v3: 64 merged blocks, single sync domain
  k_lstm_fused<<<64, 512, 0, stream>>>(X0, h0h, h1h, hdec,
                                       Whh0b, Wih1b, Whh1b, bih1, bhh1, flags);
  // decp = hdec @ Wdec^T              (M=256, N=512, K=1024)
  k_gemm_bias<<<32, 256, 0, stream>>>(hdec, Wdec, nullptr, nullptr, decp, 256, 512, 1024);
  // joint v4: barrier-free self-paced waves, 1 block/CU
  k_joint<<<512, 512, 0, stream>>>(encp, decp, Woutb, bout, out);
}

// Round 12
// 578.507 us; speedup vs baseline: 1.5097x; 1.5097x over previous
//
#include <hip/hip_runtime.h>
#include <stdint.h>

typedef short bf16x8 __attribute__((ext_vector_type(8)));
typedef float f32x4 __attribute__((ext_vector_type(4)));

__device__ __forceinline__ unsigned short f2bf(float f) {
  union { float f; unsigned int i; } v; v.f = f;
  unsigned int r = v.i + 0x7FFF + ((v.i >> 16) & 1);
  return (unsigned short)(r >> 16);
}
__device__ __forceinline__ float bfu2f(unsigned short u) {
  union { unsigned int i; float f; } v; v.i = ((unsigned int)u) << 16; return v.f;
}
__device__ __forceinline__ void gload_lds16(const void* g, void* l) {
  __builtin_amdgcn_global_load_lds(
      (const __attribute__((address_space(1))) unsigned int*)g,
      (__attribute__((address_space(3))) unsigned int*)l,
      16, 0, 0);
}

// ---------------- convert f32 weights -> bf16 (Whh0, Wih1, Whh1, Wout) ----------------
__global__ __launch_bounds__(256) void k_cvt(const float* __restrict__ s0, const float* __restrict__ s1,
                                             const float* __restrict__ s2, const float* __restrict__ s3,
                                             unsigned short* __restrict__ d0, unsigned short* __restrict__ d1,
                                             unsigned short* __restrict__ d2, unsigned short* __restrict__ d3) {
  int j = blockIdx.x * 256 + threadIdx.x;   // 6656*256 = 1,703,936 vec8 jobs exactly
  const float* s; unsigned short* d; int o;
  if (j < 524288)       { s = s0; d = d0; o = j; }
  else if (j < 1048576) { s = s1; d = d1; o = j - 524288; }
  else if (j < 1572864) { s = s2; d = d2; o = j - 1048576; }
  else                  { s = s3; d = d3; o = j - 1572864; }
  size_t off = (size_t)o * 8;
  f32x4 v0 = *(const f32x4*)(s + off);
  f32x4 v1 = *(const f32x4*)(s + off + 4);
  bf16x8 r;
#pragma unroll
  for (int k = 0; k < 4; k++) { r[k] = (short)f2bf(v0[k]); r[4 + k] = (short)f2bf(v1[k]); }
  *(bf16x8*)(d + off) = r;
}

// ---------------- prep: embedding gather (f32) + zero state + zero flags ----------------
__global__ __launch_bounds__(256) void k_prep(const int* __restrict__ ys,
                                              const float* __restrict__ embed,
                                              float* __restrict__ eys,
                                              float* __restrict__ h0h, float* __restrict__ h1h,
                                              int* __restrict__ flags) {
  int idx = blockIdx.x * 256 + threadIdx.x;   // 16384 threads
  int row = idx >> 6;
  int e = (idx & 63) * 8;
  int y = ys[row];
  f32x4 v0 = {0.f, 0.f, 0.f, 0.f}, v1 = {0.f, 0.f, 0.f, 0.f};
  if (y != 0) {
    v0 = *(const f32x4*)(embed + (size_t)y * 512 + e);
    v1 = *(const f32x4*)(embed + (size_t)y * 512 + e + 4);
  }
  *(f32x4*)(eys + (size_t)row * 512 + e) = v0;
  *(f32x4*)(eys + (size_t)row * 512 + e + 4) = v1;
  if (idx < 4096) { h0h[idx] = 0.f; h1h[idx] = 0.f; }
  if (idx < 64) flags[idx] = 0;
}

// -------- generic small GEMM: C = A(f32 MxK) @ W(f32 NxK)^T + b1 + b2; C f32 or bf16 ----
__global__ __launch_bounds__(256) void k_gemm_bias(const float* __restrict__ A,
                                                   const float* __restrict__ W,
                                                   const float* __restrict__ b1,
                                                   const float* __restrict__ b2,
                                                   void* __restrict__ Cout, int obf,
                                                   int M, int N, int K) {
  __shared__ unsigned short Als[64][40];
  __shared__ unsigned short Wls[64][40];
  int tid = threadIdx.x;
  int lane = tid & 63, wid = tid >> 6;
  int mtiles = M >> 6;
  int mt = blockIdx.x % mtiles, nt = blockIdx.x / mtiles;
  int srow = tid >> 2, sseg = tid & 3;
  f32x4 acc[4];
#pragma unroll
  for (int nf = 0; nf < 4; nf++) acc[nf] = (f32x4){0.f, 0.f, 0.f, 0.f};

  for (int kc = 0; kc < K; kc += 32) {
    const float* ap = A + (size_t)(mt * 64 + srow) * K + kc + sseg * 8;
    const float* wp = W + (size_t)(nt * 64 + srow) * K + kc + sseg * 8;
    f32x4 a0 = *(const f32x4*)ap, a1 = *(const f32x4*)(ap + 4);
    f32x4 w0 = *(const f32x4*)wp, w1 = *(const f32x4*)(wp + 4);
    bf16x8 av, wv;
#pragma unroll
    for (int k = 0; k < 4; k++) {
      av[k] = (short)f2bf(a0[k]); av[4 + k] = (short)f2bf(a1[k]);
      wv[k] = (short)f2bf(w0[k]); wv[4 + k] = (short)f2bf(w1[k]);
    }
    __syncthreads();
    *(bf16x8*)(&Als[srow][sseg * 8]) = av;
    *(bf16x8*)(&Wls[srow][sseg * 8]) = wv;
    __syncthreads();
    bf16x8 af = *(const bf16x8*)(&Als[wid * 16 + (lane & 15)][(lane >> 4) * 8]);
#pragma unroll
    for (int nf = 0; nf < 4; nf++) {
      bf16x8 bf = *(const bf16x8*)(&Wls[nf * 16 + (lane & 15)][(lane >> 4) * 8]);
      acc[nf] = __builtin_amdgcn_mfma_f32_16x16x32_bf16(af, bf, acc[nf], 0, 0, 0);
    }
  }
  int rloc = (lane >> 4) * 4;
  int col0 = lane & 15;
#pragma unroll
  for (int nf = 0; nf < 4; nf++) {
    int n = nt * 64 + nf * 16 + col0;
    float bias = 0.f;
    if (b1) bias += b1[n];
    if (b2) bias += b2[n];
#pragma unroll
    for (int r = 0; r < 4; r++) {
      int m = mt * 64 + wid * 16 + rloc + r;
      float v = acc[nf][r] + bias;
      if (obf) ((unsigned short*)Cout)[(size_t)m * N + n] = f2bf(v);
      else     ((float*)Cout)[(size_t)m * N + n] = v;
    }
  }
}

// ---------------- fused LSTM v3: 64 merged blocks, single sync domain (unchanged) ------
__global__ __launch_bounds__(512, 2) void k_lstm_fused(
    const float* __restrict__ X0,            // (B,U,4096)  eys@Wih0^T + bih0 + bhh0
    float* __restrict__ h0h,                 // (65,B,1024)
    float* __restrict__ h1h,                 // (65,B,1024)
    float* __restrict__ hdec,                // (B,U,1024) f32
    const unsigned short* __restrict__ W_hh0,
    const unsigned short* __restrict__ W_ih1,
    const unsigned short* __restrict__ W_hh1,
    const float* __restrict__ b_ih1,
    const float* __restrict__ b_hh1,
    int* __restrict__ flags) {               // 64 flags
  __shared__ unsigned short X_lds[4][2064];  // 4 batches x 2048 k (+16 pad)
  __shared__ float red0[8][4][16][4];        // 8 KB
  __shared__ float red1[8][4][16][4];        // 8 KB
  __shared__ float gsum[2][4][16][4];        // 2 KB
  int tid = threadIdx.x;
  int lane = tid & 63, w = tid >> 6;
  int bid = blockIdx.x;                      // 0..63
  int base = bid * 16;

  bf16x8 wf0[4][4];    // [gate][ks], layer0: K=128 per wave
  bf16x8 wf1[4][8];    // layer1: K=256 per wave (k<1024 -> Wih1, else Whh1)
  int ch = lane & 15;
  int kb0 = w * 128, kb1 = w * 256;
  int klo = (lane >> 4) << 3;
#pragma unroll
  for (int nt = 0; nt < 4; nt++) {
    int grow = nt * 1024 + base + ch;
#pragma unroll
    for (int ks = 0; ks < 4; ks++)
      wf0[nt][ks] = *(const bf16x8*)(W_hh0 + (size_t)grow * 1024 + kb0 + ks * 32 + klo);
#pragma unroll
    for (int ks = 0; ks < 8; ks++) {
      int k = kb1 + ks * 32 + klo;
      const unsigned short* src = (k < 1024) ? (W_ih1 + (size_t)grow * 1024 + k)
                                             : (W_hh1 + (size_t)grow * 1024 + (k - 1024));
      wf1[nt][ks] = *(const bf16x8*)src;
    }
  }

  float creg = 0.f;
  float bs0 = 0.f, bs1 = 0.f, bs2 = 0.f, bs3 = 0.f;
  int gch = (tid & 63) >> 2, gb = tid & 3;
  if (tid >= 64 && tid < 128) {
    int c = base + gch;
    bs0 = b_ih1[c] + b_hh1[c];
    bs1 = b_ih1[1024 + c] + b_hh1[1024 + c];
    bs2 = b_ih1[2048 + c] + b_hh1[2048 + c];
    bs3 = b_ih1[3072 + c] + b_hh1[3072 + c];
  }

  int ar = ch & 3;
  for (int p = 0; p <= 64; p++) {
    bool act0 = (p < 64), act1 = (p >= 1);
    if (p > 0) {
      if (w == 0) {
        while (true) {
          int f = __hip_atomic_load(&flags[lane], __ATOMIC_RELAXED, __HIP_MEMORY_SCOPE_AGENT);
          if (__all(f >= p)) break;
          __builtin_amdgcn_s_sleep(1);
        }
      }
      __syncthreads();
    }
    {
      int b = tid >> 7, k0 = (tid & 127) * 16;
      if (k0 < 1024 || act1) {
        const float* fsrc = (k0 < 1024) ? (h0h + (size_t)p * 4096 + b * 1024 + k0)
                                        : (h1h + (size_t)(p - 1) * 4096 + b * 1024 + (k0 - 1024));
        const unsigned long long* s8 = (const unsigned long long*)fsrc;
        unsigned long long v[8];
#pragma unroll
        for (int i = 0; i < 8; i++)
          v[i] = __hip_atomic_load(s8 + i, __ATOMIC_RELAXED, __HIP_MEMORY_SCOPE_AGENT);
        bf16x8 r0, r1;
#pragma unroll
        for (int i = 0; i < 4; i++) {
          union { unsigned long long u; float f[2]; } cv; cv.u = v[i];
          r0[2 * i] = (short)f2bf(cv.f[0]); r0[2 * i + 1] = (short)f2bf(cv.f[1]);
        }
#pragma unroll
        for (int i = 0; i < 4; i++) {
          union { unsigned long long u; float f[2]; } cv; cv.u = v[4 + i];
          r1[2 * i] = (short)f2bf(cv.f[0]); r1[2 * i + 1] = (short)f2bf(cv.f[1]);
        }
        *(bf16x8*)&X_lds[b][k0] = r0;
        *(bf16x8*)&X_lds[b][k0 + 8] = r1;
      }
    }
    __syncthreads();

    if (act0) {
      f32x4 acc[4];
#pragma unroll
      for (int nt = 0; nt < 4; nt++) acc[nt] = (f32x4){0.f, 0.f, 0.f, 0.f};
#pragma unroll
      for (int ks = 0; ks < 4; ks++) {
        bf16x8 a = *(const bf16x8*)&X_lds[ar][kb0 + ks * 32 + klo];
#pragma unroll
        for (int nt = 0; nt < 4; nt++)
          acc[nt] = __builtin_amdgcn_mfma_f32_16x16x32_bf16(a, wf0[nt][ks], acc[nt], 0, 0, 0);
      }
      if (lane < 16) {
#pragma unroll
        for (int nt = 0; nt < 4; nt++) *(f32x4*)&red0[w][nt][lane][0] = acc[nt];
      }
    }
    if (act1) {
      f32x4 acc[4];
#pragma unroll
      for (int nt = 0; nt < 4; nt++) acc[nt] = (f32x4){0.f, 0.f, 0.f, 0.f};
#pragma unroll
      for (int ks = 0; ks < 8; ks++) {
        bf16x8 a = *(const bf16x8*)&X_lds[ar][kb1 + ks * 32 + klo];
#pragma unroll
        for (int nt = 0; nt < 4; nt++)
          acc[nt] = __builtin_amdgcn_mfma_f32_16x16x32_bf16(a, wf1[nt][ks], acc[nt], 0, 0, 0);
      }
      if (lane < 16) {
#pragma unroll
        for (int nt = 0; nt < 4; nt++) *(f32x4*)&red1[w][nt][lane][0] = acc[nt];
      }
    }
    __syncthreads();
    {
      int layer = tid >> 8, nt = (tid >> 6) & 3, cc = (tid >> 2) & 15, q = tid & 3;
      const float (*rp)[4][16][4] = layer ? red1 : red0;
      float s = 0.f;
#pragma unroll
      for (int w8 = 0; w8 < 8; w8++) s += rp[w8][nt][cc][q];
      gsum[layer][nt][cc][q] = s;
    }
    __syncthreads();
    if (tid < 128) {
      int layer = tid >> 6;
      bool act = layer ? act1 : act0;
      if (act) {
        float gi = gsum[layer][0][gch][gb], gf = gsum[layer][1][gch][gb];
        float gg = gsum[layer][2][gch][gb], go = gsum[layer][3][gch][gb];
        if (layer == 0) {
          const float* x0p = X0 + ((size_t)(gb * 64 + p)) * 4096 + base + gch;
          gi += x0p[0]; gf += x0p[1024]; gg += x0p[2048]; go += x0p[3072];
        } else {
          gi += bs0; gf += bs1; gg += bs2; go += bs3;
        }
        float ii = 1.f / (1.f + __expf(-gi));
        float ff = 1.f / (1.f + __expf(-gf));
        float oo = 1.f / (1.f + __expf(-go));
        float cn = ff * creg + ii * tanhf(gg);
        creg = cn;
        float hn = oo * tanhf(cn);
        if (layer == 0) {
          __hip_atomic_store(&h0h[(size_t)(p + 1) * 4096 + gb * 1024 + base + gch], hn,
                             __ATOMIC_RELAXED, __HIP_MEMORY_SCOPE_AGENT);
        } else {
          __hip_atomic_store(&h1h[(size_t)p * 4096 + gb * 1024 + base + gch], hn,
                             __ATOMIC_RELAXED, __HIP_MEMORY_SCOPE_AGENT);
          hdec[((size_t)(gb * 64 + (p - 1))) * 1024 + base + gch] = hn;
        }
      }
    }
    asm volatile("s_waitcnt vmcnt(0)" ::: "memory");
    __syncthreads();
    if (tid == 0 && p < 64)
      __hip_atomic_store(&flags[bid], p + 1, __ATOMIC_RELAXED, __HIP_MEMORY_SCOPE_AGENT);
  }
}

// ---------------- k_z: Z[m][k] = tanh(encp[b,t,k] + decp[b,u,k]) as bf16 --------------
// m = (b*128+t)*64+u, 32768 x 512. encp/decp stored bf16.
__global__ __launch_bounds__(256) void k_z(const unsigned short* __restrict__ encpb, // (512,512) bf16
                                           const unsigned short* __restrict__ decpb, // (256,512) bf16
                                           unsigned short* __restrict__ Z) {
  int idx = blockIdx.x * 256 + threadIdx.x;   // 2,097,152 jobs (8192 blocks)
  int m = idx >> 6;
  int k0 = (idx & 63) * 8;
  int bt = m >> 6;                            // b*128+t
  int b = m >> 13, u = m & 63;
  bf16x8 ev = *(const bf16x8*)(encpb + (size_t)bt * 512 + k0);
  bf16x8 dv = *(const bf16x8*)(decpb + (size_t)(b * 64 + u) * 512 + k0);
  bf16x8 r;
#pragma unroll
  for (int j = 0; j < 8; j++) {
    float x = bfu2f((unsigned short)ev[j]) + bfu2f((unsigned short)dv[j]);
    float e = __expf(x + x);
    r[j] = (short)f2bf(1.f - 2.f / (e + 1.f));
  }
  *(bf16x8*)(Z + (size_t)m * 512 + k0) = r;
}

// ---------------- k_gemm_out: out = Z @ Wout^T + bout, Wout slice LDS-resident --------
// 256 blocks = 16 m-parts x 16 n-groups (bid&15 = mpart -> same-mpart blocks share XCD).
// Block: Wout rows [ngroup*128,+128) x 512k staged ONCE into 128KB LDS; each of 8 waves
// streams 256 Z-rows (4 m-groups of 64) through MFMA. 1 block/CU.
__global__ __launch_bounds__(512, 2) void k_gemm_out(const unsigned short* __restrict__ Z,    // (32768,512) bf16
                                                     const unsigned short* __restrict__ Wout, // (2048,512) bf16
                                                     const float* __restrict__ bout,          // (2048) f32
                                                     float* __restrict__ out) {               // (32768,2048) f32
  __shared__ unsigned short Wls[8][8192];   // 8 k-chunks x (128 n-rows x 64 k, swizzled)
  int tid = threadIdx.x;
  int lane = tid & 63, wid = tid >> 6;
  int bid = blockIdx.x;
  int mpart = bid & 15, ngroup = bid >> 4;

  // ---- stage Wout slice once (16 gload_lds16 per thread) ----
#pragma unroll
  for (int kc = 0; kc < 8; kc++) {
    unsigned short* dst = &Wls[kc][0];
#pragma unroll
    for (int q = 0; q < 2; q++) {
      int idx = tid + q * 512;
      int n = idx >> 3, sl = idx & 7;
      int ss = sl ^ (n & 7);
      gload_lds16(Wout + (size_t)(ngroup * 128 + n) * 512 + kc * 64 + ss * 8, dst + idx * 8);
    }
  }
  // ---- bias preload (8 regs) ----
  float bb[8];
#pragma unroll
  for (int nf = 0; nf < 8; nf++) bb[nf] = bout[ngroup * 128 + nf * 16 + (lane & 15)];
  asm volatile("s_waitcnt vmcnt(0)" ::: "memory");
  __syncthreads();

  int rowwave = mpart * 2048 + wid * 256;     // wave's 256 rows
  int ocol0 = ngroup * 128;
  for (int mg = 0; mg < 4; mg++) {
    int rowbase = rowwave + mg * 64;
    f32x4 acc[4][8];
#pragma unroll
    for (int mf = 0; mf < 4; mf++)
#pragma unroll
      for (int nf = 0; nf < 8; nf++) acc[mf][nf] = (f32x4){0.f, 0.f, 0.f, 0.f};

#pragma unroll
    for (int ks = 0; ks < 16; ks++) {
      bf16x8 a[4];
#pragma unroll
      for (int mf = 0; mf < 4; mf++) {
        int r = rowbase + mf * 16 + (lane & 15);
        a[mf] = *(const bf16x8*)(Z + (size_t)r * 512 + ks * 32 + ((lane >> 4) << 3));
      }
      const unsigned short* Wb = &Wls[ks >> 1][0];
      int slot = (ks & 1) * 4 + (lane >> 4);
#pragma unroll
      for (int nf = 0; nf < 8; nf++) {
        int nl = nf * 16 + (lane & 15);
        int phys = slot ^ (nl & 7);
        bf16x8 bfr = *(const bf16x8*)(Wb + nl * 64 + phys * 8);
#pragma unroll
        for (int mf = 0; mf < 4; mf++)
          acc[mf][nf] = __builtin_amdgcn_mfma_f32_16x16x32_bf16(a[mf], bfr, acc[mf][nf], 0, 0, 0);
      }
    }
    // ---- epilogue: direct NT stores (64B row segments) ----
#pragma unroll
    for (int mf = 0; mf < 4; mf++) {
      int rb = rowbase + mf * 16 + ((lane >> 4) << 2);
#pragma unroll
      for (int nf = 0; nf < 8; nf++) {
        int o = ocol0 + nf * 16 + (lane & 15);
        float bias = bb[nf];
#pragma unroll
        for (int q = 0; q < 4; q++)
          __builtin_nontemporal_store(acc[mf][nf][q] + bias, &out[(size_t)(rb + q) * 2048 + o]);
      }
    }
  }
}

// ---------------- launch ----------------
extern "C" void kernel_launch(void* const* d_in, const int* in_sizes, int n_in,
                              void* d_out, int out_size, void* d_ws, size_t ws_size,
                              hipStream_t stream) {
  const float* hs   = (const float*)d_in[0];
  const int*   ys   = (const int*)d_in[1];
  const float* emb  = (const float*)d_in[2];
  const float* Wih0 = (const float*)d_in[3];
  const float* Whh0 = (const float*)d_in[4];
  const float* bih0 = (const float*)d_in[5];
  const float* bhh0 = (const float*)d_in[6];
  const float* Wih1 = (const float*)d_in[7];
  const float* Whh1 = (const float*)d_in[8];
  const float* bih1 = (const float*)d_in[9];
  const float* bhh1 = (const float*)d_in[10];
  const float* Wenc = (const float*)d_in[11];
  const float* benc = (const float*)d_in[12];
  const float* Wdec = (const float*)d_in[13];
  const float* Wout = (const float*)d_in[14];
  const float* bout = (const float*)d_in[15];

  // Workspace map (liveness-overlapped; peak 36,438,016 B < prior 36,765,696):
  //  [0,        2,097,152)  Woutb   bf16 (live whole run)
  //  [2,097,152 2,621,440)  encpb   bf16 (live: enc-gemm .. k_z)
  //  [2,621,440 2,883,584)  decpb   bf16 (live: dec-gemm .. k_z)
  //  [2,883,584 36,438,016) Z       bf16 (written by k_z; overlays all below)
  //    overlaid (dead before k_z): eys, X0, h0h, h1h, hdec, flags, Whh0b/Wih1b/Whh1b
  char* ws = (char*)d_ws;
  unsigned short* Woutb = (unsigned short*)(ws + 0);
  unsigned short* encpb = (unsigned short*)(ws + 2097152);
  unsigned short* decpb = (unsigned short*)(ws + 2621440);
  unsigned short* Z     = (unsigned short*)(ws + 2883584);
  float*          eys   = (float*)(ws + 2883584);            //   524,288
  float*          X0    = (float*)(ws + 3407872);            // 4,194,304
  float*          h0h   = (float*)(ws + 7602176);            // 1,064,960
  float*          h1h   = (float*)(ws + 8667136);            // 1,064,960
  float*          hdec  = (float*)(ws + 9732096);            // 1,048,576
  int*            flags = (int*)(ws + 10780672);             //     1,024
  unsigned short* Whh0b = (unsigned short*)(ws + 10781696);  // 8,388,608
  unsigned short* Wih1b = (unsigned short*)(ws + 19170304);  // 8,388,608
  unsigned short* Whh1b = (unsigned short*)(ws + 27558912);  // 8,388,608 -> ends 35,947,520
  float*          out   = (float*)d_out;

  // weight conversion (bf16 LSTM recurrent mats + Wout)
  k_cvt<<<6656, 256, 0, stream>>>(Whh0, Wih1, Whh1, Wout, Whh0b, Wih1b, Whh1b, Woutb);
  k_prep<<<64, 256, 0, stream>>>(ys, emb, eys, h0h, h1h, flags);
  // X0 = eys @ Wih0^T + bih0 + bhh0   (f32 out; M=256, N=4096, K=512)
  k_gemm_bias<<<256, 256, 0, stream>>>(eys, Wih0, bih0, bhh0, X0, 0, 256, 4096, 512);
  // encpb = bf16(hs @ Wenc^T + benc)  (M=512, N=512, K=512)
  k_gemm_bias<<<64, 256, 0, stream>>>(hs, Wenc, benc, nullptr, encpb, 1, 512, 512, 512);
  // fused LSTM
  k_lstm_fused<<<64, 512, 0, stream>>>(X0, h0h, h1h, hdec,
                                       Whh0b, Wih1b, Whh1b, bih1, bhh1, flags);
  // decpb = bf16(hdec @ Wdec^T)       (M=256, N=512, K=1024)
  k_gemm_bias<<<32, 256, 0, stream>>>(hdec, Wdec, nullptr, nullptr, decpb, 1, 256, 512, 1024);
  // Z = tanh(enc + dec) materialized bf16
  k_z<<<8192, 256, 0, stream>>>(encpb, decpb, Z);
  // out = Z @ Wout^T + bout  (Wout slice LDS-resident per block)
  k_gemm_out<<<256, 512, 0, stream>>>(Z, Woutb, bout, out);
}

// Round 13
// 553.938 us; speedup vs baseline: 1.5767x; 1.0444x over previous
//
#include <hip/hip_runtime.h>
#include <stdint.h>

typedef short bf16x8 __attribute__((ext_vector_type(8)));
typedef float f32x4 __attribute__((ext_vector_type(4)));
typedef unsigned int u32x4 __attribute__((ext_vector_type(4)));

__device__ __forceinline__ unsigned short f2bf(float f) {
  union { float f; unsigned int i; } v; v.f = f;
  unsigned int r = v.i + 0x7FFF + ((v.i >> 16) & 1);
  return (unsigned short)(r >> 16);
}
__device__ __forceinline__ float bfu2f(unsigned short u) {
  union { unsigned int i; float f; } v; v.i = ((unsigned int)u) << 16; return v.f;
}
__device__ __forceinline__ void gload_lds16(const void* g, void* l) {
  __builtin_amdgcn_global_load_lds(
      (const __attribute__((address_space(1))) unsigned int*)g,
      (__attribute__((address_space(3))) unsigned int*)l,
      16, 0, 0);
}
// coherent (IC-level) 16B store: single instruction => tag+data commit atomically
__device__ __forceinline__ void store16_coh(unsigned int* p, u32x4 v) {
  asm volatile("global_store_dwordx4 %0, %1, off sc0 sc1" :: "v"(p), "v"(v) : "memory");
}
// coherent 6x16B gather with one waitcnt (spin body)
__device__ __forceinline__ void spin_load6(const unsigned int* p0, const unsigned int* p1,
                                           const unsigned int* p2, const unsigned int* p3,
                                           const unsigned int* p4, const unsigned int* p5,
                                           u32x4& r0, u32x4& r1, u32x4& r2,
                                           u32x4& r3, u32x4& r4, u32x4& r5) {
  asm volatile(
      "global_load_dwordx4 %0, %6, off sc0 sc1\n\t"
      "global_load_dwordx4 %1, %7, off sc0 sc1\n\t"
      "global_load_dwordx4 %2, %8, off sc0 sc1\n\t"
      "global_load_dwordx4 %3, %9, off sc0 sc1\n\t"
      "global_load_dwordx4 %4, %10, off sc0 sc1\n\t"
      "global_load_dwordx4 %5, %11, off sc0 sc1\n\t"
      "s_waitcnt vmcnt(0)"
      : "=&v"(r0), "=&v"(r1), "=&v"(r2), "=&v"(r3), "=&v"(r4), "=&v"(r5)
      : "v"(p0), "v"(p1), "v"(p2), "v"(p3), "v"(p4), "v"(p5)
      : "memory");
}

// ---------------- convert f32 weights -> bf16 (Whh0, Wih1, Whh1, Wout) ----------------
__global__ __launch_bounds__(256) void k_cvt(const float* __restrict__ s0, const float* __restrict__ s1,
                                             const float* __restrict__ s2, const float* __restrict__ s3,
                                             unsigned short* __restrict__ d0, unsigned short* __restrict__ d1,
                                             unsigned short* __restrict__ d2, unsigned short* __restrict__ d3) {
  int j = blockIdx.x * 256 + threadIdx.x;   // 6656*256 = 1,703,936 vec8 jobs exactly
  const float* s; unsigned short* d; int o;
  if (j < 524288)       { s = s0; d = d0; o = j; }
  else if (j < 1048576) { s = s1; d = d1; o = j - 524288; }
  else if (j < 1572864) { s = s2; d = d2; o = j - 1048576; }
  else                  { s = s3; d = d3; o = j - 1572864; }
  size_t off = (size_t)o * 8;
  f32x4 v0 = *(const f32x4*)(s + off);
  f32x4 v1 = *(const f32x4*)(s + off + 4);
  bf16x8 r;
#pragma unroll
  for (int k = 0; k < 4; k++) { r[k] = (short)f2bf(v0[k]); r[4 + k] = (short)f2bf(v1[k]); }
  *(bf16x8*)(d + off) = r;
}

// ---------------- prep: embedding gather (f32) + zero exchange buffers ----------------
__global__ __launch_bounds__(256) void k_prep(const int* __restrict__ ys,
                                              const float* __restrict__ embed,
                                              float* __restrict__ eys,
                                              unsigned int* __restrict__ exch) {
  int idx = blockIdx.x * 256 + threadIdx.x;   // 16384 threads
  int row = idx >> 6;
  int e = (idx & 63) * 8;
  int y = ys[row];
  f32x4 v0 = {0.f, 0.f, 0.f, 0.f}, v1 = {0.f, 0.f, 0.f, 0.f};
  if (y != 0) {
    v0 = *(const f32x4*)(embed + (size_t)y * 512 + e);
    v1 = *(const f32x4*)(embed + (size_t)y * 512 + e + 4);
  }
  *(f32x4*)(eys + (size_t)row * 512 + e) = v0;
  *(f32x4*)(eys + (size_t)row * 512 + e + 4) = v1;
  for (int j = idx; j < 36864; j += 16384) exch[j] = 0u;  // tags 0 + h=0 initial state
}

// -------- generic small GEMM: C = A(f32 MxK) @ W(f32 NxK)^T + b1 + b2; C f32 or bf16 ----
__global__ __launch_bounds__(256) void k_gemm_bias(const float* __restrict__ A,
                                                   const float* __restrict__ W,
                                                   const float* __restrict__ b1,
                                                   const float* __restrict__ b2,
                                                   void* __restrict__ Cout, int obf,
                                                   int M, int N, int K) {
  __shared__ unsigned short Als[64][40];
  __shared__ unsigned short Wls[64][40];
  int tid = threadIdx.x;
  int lane = tid & 63, wid = tid >> 6;
  int mtiles = M >> 6;
  int mt = blockIdx.x % mtiles, nt = blockIdx.x / mtiles;
  int srow = tid >> 2, sseg = tid & 3;
  f32x4 acc[4];
#pragma unroll
  for (int nf = 0; nf < 4; nf++) acc[nf] = (f32x4){0.f, 0.f, 0.f, 0.f};

  for (int kc = 0; kc < K; kc += 32) {
    const float* ap = A + (size_t)(mt * 64 + srow) * K + kc + sseg * 8;
    const float* wp = W + (size_t)(nt * 64 + srow) * K + kc + sseg * 8;
    f32x4 a0 = *(const f32x4*)ap, a1 = *(const f32x4*)(ap + 4);
    f32x4 w0 = *(const f32x4*)wp, w1 = *(const f32x4*)(wp + 4);
    bf16x8 av, wv;
#pragma unroll
    for (int k = 0; k < 4; k++) {
      av[k] = (short)f2bf(a0[k]); av[4 + k] = (short)f2bf(a1[k]);
      wv[k] = (short)f2bf(w0[k]); wv[4 + k] = (short)f2bf(w1[k]);
    }
    __syncthreads();
    *(bf16x8*)(&Als[srow][sseg * 8]) = av;
    *(bf16x8*)(&Wls[srow][sseg * 8]) = wv;
    __syncthreads();
    bf16x8 af = *(const bf16x8*)(&Als[wid * 16 + (lane & 15)][(lane >> 4) * 8]);
#pragma unroll
    for (int nf = 0; nf < 4; nf++) {
      bf16x8 bf = *(const bf16x8*)(&Wls[nf * 16 + (lane & 15)][(lane >> 4) * 8]);
      acc[nf] = __builtin_amdgcn_mfma_f32_16x16x32_bf16(af, bf, acc[nf], 0, 0, 0);
    }
  }
  int rloc = (lane >> 4) * 4;
  int col0 = lane & 15;
#pragma unroll
  for (int nf = 0; nf < 4; nf++) {
    int n = nt * 64 + nf * 16 + col0;
    float bias = 0.f;
    if (b1) bias += b1[n];
    if (b2) bias += b2[n];
#pragma unroll
    for (int r = 0; r < 4; r++) {
      int m = mt * 64 + wid * 16 + rloc + r;
      float v = acc[nf][r] + bias;
      if (obf) ((unsigned short*)Cout)[(size_t)m * N + n] = f2bf(v);
      else     ((float*)Cout)[(size_t)m * N + n] = v;
    }
  }
}

// ---------------- fused LSTM v4: tag-embedded exchange, no flags ----------------------
// 64 blocks x 512 threads. Block b owns channels [b*16,b*16+16) of BOTH layers.
// Exchange record: 16B = {3 x f32 h, u32 tag=step}, written by ONE dwordx4 sc0 sc1 store
// (commits atomically). Per layer-step: 64 blocks x 22 units. Parity double-buffer.
// Consumers spin per-thread on own 6 units until tags match; induction guarantees
// 2 buffers suffice (h[q+1] all-fresh => every block finished reading h[q-1..q]).
__global__ __launch_bounds__(512) void k_lstm_fused(
    const float* __restrict__ X0,            // (B,U,4096)  eys@Wih0^T + bih0 + bhh0
    float* __restrict__ hdec,                // (B,U,1024) f32
    const unsigned short* __restrict__ W_hh0,
    const unsigned short* __restrict__ W_ih1,
    const unsigned short* __restrict__ W_hh1,
    const float* __restrict__ b_ih1,
    const float* __restrict__ b_hh1,
    unsigned int* __restrict__ exch) {       // h0:[2][9216]dw, h1:+18432:[2][9216]dw
  __shared__ unsigned short X_lds[4][2064];  // 4 batches x 2048 k (+16 pad)
  __shared__ float red0[8][4][16][4];
  __shared__ float red1[8][4][16][4];
  __shared__ float gsum[2][4][16][4];
  int tid = threadIdx.x;
  int lane = tid & 63, w = tid >> 6;
  int bid = blockIdx.x;                      // 0..63
  int base = bid * 16;

  // ---- preload weight B-frags (identical fragment scheme to passing r8-r12) ----
  bf16x8 wf0[4][4];
  bf16x8 wf1[4][8];
  int ch = lane & 15;
  int kb0 = w * 128, kb1 = w * 256;
  int klo = (lane >> 4) << 3;
#pragma unroll
  for (int nt = 0; nt < 4; nt++) {
    int grow = nt * 1024 + base + ch;
#pragma unroll
    for (int ks = 0; ks < 4; ks++)
      wf0[nt][ks] = *(const bf16x8*)(W_hh0 + (size_t)grow * 1024 + kb0 + ks * 32 + klo);
#pragma unroll
    for (int ks = 0; ks < 8; ks++) {
      int k = kb1 + ks * 32 + klo;
      const unsigned short* src = (k < 1024) ? (W_ih1 + (size_t)grow * 1024 + k)
                                             : (W_hh1 + (size_t)grow * 1024 + (k - 1024));
      wf1[nt][ks] = *(const bf16x8*)src;
    }
  }

  float creg = 0.f;
  float bs0 = 0.f, bs1 = 0.f, bs2 = 0.f, bs3 = 0.f;
  int gch = (tid & 63) >> 2, gb = tid & 3;
  if (tid >= 64 && tid < 128) {
    int c = base + gch;
    bs0 = b_ih1[c] + b_hh1[c];
    bs1 = b_ih1[1024 + c] + b_hh1[1024 + c];
    bs2 = b_ih1[2048 + c] + b_hh1[2048 + c];
    bs3 = b_ih1[3072 + c] + b_hh1[3072 + c];
  }

  // ---- consumer unit precompute: 3 unit slots (shared offsets for h0/h1) ----
  int uoff[3], upb[3], us[3]; bool uneed[3];
#pragma unroll
  for (int r = 0; r < 3; r++) {
    int u = tid + r * 512;
    uneed[r] = (u < 1408);
    int uc = uneed[r] ? u : 1407;
    int pb = uc / 22;
    int s = uc - pb * 22;
    upb[r] = pb; us[r] = s;
    uoff[r] = pb * 128 + s * 4;              // dword offset in a layer-parity buffer
  }

  int ar = ch & 3;
  for (int p = 0; p <= 64; p++) {
    bool act0 = (p < 64), act1 = (p >= 1);
    // ---- spin-validate + load h units (self-validating records) ----
    {
      unsigned int* b0 = exch + (unsigned)(p & 1) * 9216;
      unsigned int* b1 = exch + 18432 + (unsigned)((p - 1) & 1) * 9216;
      u32x4 r0, r1, r2, r3, r4, r5;
      unsigned exp0 = (unsigned)p, exp1 = (unsigned)(p - 1);
      while (true) {
        spin_load6(b0 + uoff[0], b0 + uoff[1], b0 + uoff[2],
                   b1 + uoff[0], b1 + uoff[1], b1 + uoff[2],
                   r0, r1, r2, r3, r4, r5);
        bool ok = (!uneed[0] || r0[3] == exp0) && (!uneed[1] || r1[3] == exp0) &&
                  (!uneed[2] || r2[3] == exp0);
        if (act1)
          ok = ok && (!uneed[0] || r3[3] == exp1) && (!uneed[1] || r4[3] == exp1) &&
               (!uneed[2] || r5[3] == exp1);
        if (ok) break;
        __builtin_amdgcn_s_sleep(1);
      }
#define STAGE_UNIT(rv, rr, off1024)                                           \
      if (uneed[rv]) {                                                        \
        int pb_ = upb[rv], s_ = us[rv];                                       \
        _Pragma("unroll")                                                     \
        for (int j_ = 0; j_ < 3; j_++) {                                      \
          int i_ = 3 * s_ + j_;                                               \
          if (i_ < 64) {                                                      \
            union { unsigned int u; float f; } cv_; cv_.u = rr[j_];           \
            X_lds[i_ & 3][off1024 + pb_ * 16 + (i_ >> 2)] = f2bf(cv_.f);      \
          }                                                                   \
        }                                                                     \
      }
      STAGE_UNIT(0, r0, 0) STAGE_UNIT(1, r1, 0) STAGE_UNIT(2, r2, 0)
      if (act1) { STAGE_UNIT(0, r3, 1024) STAGE_UNIT(1, r4, 1024) STAGE_UNIT(2, r5, 1024) }
#undef STAGE_UNIT
    }
    __syncthreads();

    // ---- layer0 MFMA ----
    if (act0) {
      f32x4 acc[4];
#pragma unroll
      for (int nt = 0; nt < 4; nt++) acc[nt] = (f32x4){0.f, 0.f, 0.f, 0.f};
#pragma unroll
      for (int ks = 0; ks < 4; ks++) {
        bf16x8 a = *(const bf16x8*)&X_lds[ar][kb0 + ks * 32 + klo];
#pragma unroll
        for (int nt = 0; nt < 4; nt++)
          acc[nt] = __builtin_amdgcn_mfma_f32_16x16x32_bf16(a, wf0[nt][ks], acc[nt], 0, 0, 0);
      }
      if (lane < 16) {
#pragma unroll
        for (int nt = 0; nt < 4; nt++) *(f32x4*)&red0[w][nt][lane][0] = acc[nt];
      }
    }
    // ---- layer1 MFMA ----
    if (act1) {
      f32x4 acc[4];
#pragma unroll
      for (int nt = 0; nt < 4; nt++) acc[nt] = (f32x4){0.f, 0.f, 0.f, 0.f};
#pragma unroll
      for (int ks = 0; ks < 8; ks++) {
        bf16x8 a = *(const bf16x8*)&X_lds[ar][kb1 + ks * 32 + klo];
#pragma unroll
        for (int nt = 0; nt < 4; nt++)
          acc[nt] = __builtin_amdgcn_mfma_f32_16x16x32_bf16(a, wf1[nt][ks], acc[nt], 0, 0, 0);
      }
      if (lane < 16) {
#pragma unroll
        for (int nt = 0; nt < 4; nt++) *(f32x4*)&red1[w][nt][lane][0] = acc[nt];
      }
    }
    __syncthreads();
    // ---- reduce 8 wave-partials ----
    {
      int layer = tid >> 8, nt = (tid >> 6) & 3, cc = (tid >> 2) & 15, q = tid & 3;
      const float (*rp)[4][16][4] = layer ? red1 : red0;
      float s = 0.f;
#pragma unroll
      for (int w8 = 0; w8 < 8; w8++) s += rp[w8][nt][cc][q];
      gsum[layer][nt][cc][q] = s;
    }
    __syncthreads();
    // ---- gates + tag-embedded export (waves 0,1 only; no cross-wave ordering) ----
    if (tid < 128) {
      int layer = tid >> 6;
      bool act = layer ? act1 : act0;
      if (act) {
        float gi = gsum[layer][0][gch][gb], gf = gsum[layer][1][gch][gb];
        float gg = gsum[layer][2][gch][gb], go = gsum[layer][3][gch][gb];
        if (layer == 0) {
          const float* x0p = X0 + ((size_t)(gb * 64 + p)) * 4096 + base + gch;
          gi += x0p[0]; gf += x0p[1024]; gg += x0p[2048]; go += x0p[3072];
        } else {
          gi += bs0; gf += bs1; gg += bs2; go += bs3;
        }
        float ii = 1.f / (1.f + __expf(-gi));
        float ff = 1.f / (1.f + __expf(-gf));
        float oo = 1.f / (1.f + __expf(-go));
        float cn = ff * creg + ii * tanhf(gg);
        creg = cn;
        float hn = oo * tanhf(cn);
        if (layer == 1)
          hdec[((size_t)(gb * 64 + (p - 1))) * 1024 + base + gch] = hn;
        // lane l holds v[l] = h[l&3][base+(l>>2)]; gather 3 per export unit via shfl
        int l = tid & 63;
        float v0 = __shfl(hn, 3 * l);
        float v1 = __shfl(hn, 3 * l + 1);
        float v2 = __shfl(hn, 3 * l + 2);
        if (l < 22) {
          unsigned tag = layer ? (unsigned)p : (unsigned)(p + 1);
          unsigned int* rec = exch + layer * 18432 + (tag & 1) * 9216 + bid * 128 + l * 4;
          u32x4 d;
          d[0] = __float_as_uint(v0); d[1] = __float_as_uint(v1);
          d[2] = __float_as_uint(v2); d[3] = tag;
          store16_coh(rec, d);
        }
      }
    }
    // no end-of-round barrier: next round's spin self-synchronizes
  }
}

// ---------------- k_z: Z[m][k] = tanh(encp[b,t,k] + decp[b,u,k]) as bf16 --------------
__global__ __launch_bounds__(256) void k_z(const unsigned short* __restrict__ encpb, // (512,512) bf16
                                           const unsigned short* __restrict__ decpb, // (256,512) bf16
                                           unsigned short* __restrict__ Z) {
  int idx = blockIdx.x * 256 + threadIdx.x;   // 2,097,152 jobs (8192 blocks)
  int m = idx >> 6;
  int k0 = (idx & 63) * 8;
  int bt = m >> 6;                            // b*128+t
  int b = m >> 13, u = m & 63;
  bf16x8 ev = *(const bf16x8*)(encpb + (size_t)bt * 512 + k0);
  bf16x8 dv = *(const bf16x8*)(decpb + (size_t)(b * 64 + u) * 512 + k0);
  bf16x8 r;
#pragma unroll
  for (int j = 0; j < 8; j++) {
    float x = bfu2f((unsigned short)ev[j]) + bfu2f((unsigned short)dv[j]);
    float e = __expf(x + x);
    r[j] = (short)f2bf(1.f - 2.f / (e + 1.f));
  }
  *(bf16x8*)(Z + (size_t)m * 512 + k0) = r;
}

// ---------------- k_gemm_out: out = Z @ Wout^T + bout, Wout slice LDS-resident --------
__global__ __launch_bounds__(512, 2) void k_gemm_out(const unsigned short* __restrict__ Z,    // (32768,512) bf16
                                                     const unsigned short* __restrict__ Wout, // (2048,512) bf16
                                                     const float* __restrict__ bout,          // (2048) f32
                                                     float* __restrict__ out) {               // (32768,2048) f32
  __shared__ unsigned short Wls[8][8192];   // 8 k-chunks x (128 n-rows x 64 k, swizzled)
  int tid = threadIdx.x;
  int lane = tid & 63, wid = tid >> 6;
  int bid = blockIdx.x;
  int mpart = bid & 15, ngroup = bid >> 4;

#pragma unroll
  for (int kc = 0; kc < 8; kc++) {
    unsigned short* dst = &Wls[kc][0];
#pragma unroll
    for (int q = 0; q < 2; q++) {
      int idx = tid + q * 512;
      int n = idx >> 3, sl = idx & 7;
      int ss = sl ^ (n & 7);
      gload_lds16(Wout + (size_t)(ngroup * 128 + n) * 512 + kc * 64 + ss * 8, dst + idx * 8);
    }
  }
  float bb[8];
#pragma unroll
  for (int nf = 0; nf < 8; nf++) bb[nf] = bout[ngroup * 128 + nf * 16 + (lane & 15)];
  asm volatile("s_waitcnt vmcnt(0)" ::: "memory");
  __syncthreads();

  int rowwave = mpart * 2048 + wid * 256;
  int ocol0 = ngroup * 128;
  for (int mg = 0; mg < 4; mg++) {
    int rowbase = rowwave + mg * 64;
    f32x4 acc[4][8];
#pragma unroll
    for (int mf = 0; mf < 4; mf++)
#pragma unroll
      for (int nf = 0; nf < 8; nf++) acc[mf][nf] = (f32x4){0.f, 0.f, 0.f, 0.f};

#pragma unroll
    for (int ks = 0; ks < 16; ks++) {
      bf16x8 a[4];
#pragma unroll
      for (int mf = 0; mf < 4; mf++) {
        int r = rowbase + mf * 16 + (lane & 15);
        a[mf] = *(const bf16x8*)(Z + (size_t)r * 512 + ks * 32 + ((lane >> 4) << 3));
      }
      const unsigned short* Wb = &Wls[ks >> 1][0];
      int slot = (ks & 1) * 4 + (lane >> 4);
#pragma unroll
      for (int nf = 0; nf < 8; nf++) {
        int nl = nf * 16 + (lane & 15);
        int phys = slot ^ (nl & 7);
        bf16x8 bfr = *(const bf16x8*)(Wb + nl * 64 + phys * 8);
#pragma unroll
        for (int mf = 0; mf < 4; mf++)
          acc[mf][nf] = __builtin_amdgcn_mfma_f32_16x16x32_bf16(a[mf], bfr, acc[mf][nf], 0, 0, 0);
      }
    }
#pragma unroll
    for (int mf = 0; mf < 4; mf++) {
      int rb = rowbase + mf * 16 + ((lane >> 4) << 2);
#pragma unroll
      for (int nf = 0; nf < 8; nf++) {
        int o = ocol0 + nf * 16 + (lane & 15);
        float bias = bb[nf];
#pragma unroll
        for (int q = 0; q < 4; q++)
          __builtin_nontemporal_store(acc[mf][nf][q] + bias, &out[(size_t)(rb + q) * 2048 + o]);
      }
    }
  }
}

// ---------------- launch ----------------
extern "C" void kernel_launch(void* const* d_in, const int* in_sizes, int n_in,
                              void* d_out, int out_size, void* d_ws, size_t ws_size,
                              hipStream_t stream) {
  const float* hs   = (const float*)d_in[0];
  const int*   ys   = (const int*)d_in[1];
  const float* emb  = (const float*)d_in[2];
  const float* Wih0 = (const float*)d_in[3];
  const float* Whh0 = (const float*)d_in[4];
  const float* bih0 = (const float*)d_in[5];
  const float* bhh0 = (const float*)d_in[6];
  const float* Wih1 = (const float*)d_in[7];
  const float* Whh1 = (const float*)d_in[8];
  const float* bih1 = (const float*)d_in[9];
  const float* bhh1 = (const float*)d_in[10];
  const float* Wenc = (const float*)d_in[11];
  const float* benc = (const float*)d_in[12];
  const float* Wdec = (const float*)d_in[13];
  const float* Wout = (const float*)d_in[14];
  const float* bout = (const float*)d_in[15];

  // Workspace map (liveness-overlapped; peak 36,585,472 B):
  //  [0,        2,097,152)  Woutb  bf16
  //  [2,097,152 2,621,440)  encpb  bf16
  //  [2,621,440 2,883,584)  decpb  bf16
  //  [2,883,584 3,031,040)  exch   u32 (dedicated, NOT overlaid)
  //  [3,031,040 36,585,472) Z      bf16; overlays (dead before k_z):
  //     eys, X0, hdec, Whh0b, Wih1b, Whh1b
  char* ws = (char*)d_ws;
  unsigned short* Woutb = (unsigned short*)(ws + 0);
  unsigned short* encpb = (unsigned short*)(ws + 2097152);
  unsigned short* decpb = (unsigned short*)(ws + 2621440);
  unsigned int*   exch  = (unsigned int*)(ws + 2883584);
  unsigned short* Z     = (unsigned short*)(ws + 3031040);
  float*          eys   = (float*)(ws + 3031040);            //   524,288
  float*          X0    = (float*)(ws + 3555328);            // 4,194,304
  float*          hdec  = (float*)(ws + 7749632);            // 1,048,576
  unsigned short* Whh0b = (unsigned short*)(ws + 8798208);   // 8,388,608
  unsigned short* Wih1b = (unsigned short*)(ws + 17186816);  // 8,388,608
  unsigned short* Whh1b = (unsigned short*)(ws + 25575424);  // 8,388,608 -> 33,964,032
  float*          out   = (float*)d_out;

  k_cvt<<<6656, 256, 0, stream>>>(Whh0, Wih1, Whh1, Wout, Whh0b, Wih1b, Whh1b, Woutb);
  k_prep<<<64, 256, 0, stream>>>(ys, emb, eys, exch);
  // X0 = eys @ Wih0^T + bih0 + bhh0   (f32 out; M=256, N=4096, K=512)
  k_gemm_bias<<<256, 256, 0, stream>>>(eys, Wih0, bih0, bhh0, X0, 0, 256, 4096, 512);
  // encpb = bf16(hs @ Wenc^T + benc)  (M=512, N=512, K=512)
  k_gemm_bias<<<64, 256, 0, stream>>>(hs, Wenc, benc, nullptr, encpb, 1, 512, 512, 512);
  // fused LSTM v4: tag-embedded exchange
  k_lstm_fused<<<64, 512, 0, stream>>>(X0, hdec, Whh0b, Wih1b, Whh1b, bih1, bhh1, exch);
  // decpb = bf16(hdec @ Wdec^T)       (M=256, N=512, K=1024)
  k_gemm_bias<<<32, 256, 0, stream>>>(hdec, Wdec, nullptr, nullptr, decpb, 1, 256, 512, 1024);
  // Z = tanh(enc + dec) materialized bf16
  k_z<<<8192, 256, 0, stream>>>(encpb, decpb, Z);
  // out = Z @ Wout^T + bout (Wout slice LDS-resident per block)
  k_gemm_out<<<256, 512, 0, stream>>>(Z, Woutb, bout, out);
}

// Round 14
// 421.897 us; speedup vs baseline: 2.0702x; 1.3130x over previous
//
#include <hip/hip_runtime.h>
#include <stdint.h>

typedef short bf16x8 __attribute__((ext_vector_type(8)));
typedef float f32x4 __attribute__((ext_vector_type(4)));
typedef unsigned int u32x4 __attribute__((ext_vector_type(4)));

__device__ __forceinline__ unsigned short f2bf(float f) {
  union { float f; unsigned int i; } v; v.f = f;
  unsigned int r = v.i + 0x7FFF + ((v.i >> 16) & 1);
  return (unsigned short)(r >> 16);
}
__device__ __forceinline__ float bfu2f(unsigned short u) {
  union { unsigned int i; float f; } v; v.i = ((unsigned int)u) << 16; return v.f;
}
__device__ __forceinline__ void gload_lds16(const void* g, void* l) {
  __builtin_amdgcn_global_load_lds(
      (const __attribute__((address_space(1))) unsigned int*)g,
      (__attribute__((address_space(3))) unsigned int*)l,
      16, 0, 0);
}
// coherent (IC-level) 16B store: single instruction => tag+data commit atomically
__device__ __forceinline__ void store16_coh(unsigned int* p, u32x4 v) {
  asm volatile("global_store_dwordx4 %0, %1, off sc0 sc1" :: "v"(p), "v"(v) : "memory");
}
__device__ __forceinline__ void spin_load6(const unsigned int* p0, const unsigned int* p1,
                                           const unsigned int* p2, const unsigned int* p3,
                                           const unsigned int* p4, const unsigned int* p5,
                                           u32x4& r0, u32x4& r1, u32x4& r2,
                                           u32x4& r3, u32x4& r4, u32x4& r5) {
  asm volatile(
      "global_load_dwordx4 %0, %6, off sc0 sc1\n\t"
      "global_load_dwordx4 %1, %7, off sc0 sc1\n\t"
      "global_load_dwordx4 %2, %8, off sc0 sc1\n\t"
      "global_load_dwordx4 %3, %9, off sc0 sc1\n\t"
      "global_load_dwordx4 %4, %10, off sc0 sc1\n\t"
      "global_load_dwordx4 %5, %11, off sc0 sc1\n\t"
      "s_waitcnt vmcnt(0)"
      : "=&v"(r0), "=&v"(r1), "=&v"(r2), "=&v"(r3), "=&v"(r4), "=&v"(r5)
      : "v"(p0), "v"(p1), "v"(p2), "v"(p3), "v"(p4), "v"(p5)
      : "memory");
}
// 3 record loads + 1 probe-tag load (L0 spin body)
__device__ __forceinline__ void spin_load3p(const unsigned int* p0, const unsigned int* p1,
                                            const unsigned int* p2, const unsigned int* pp,
                                            u32x4& r0, u32x4& r1, u32x4& r2, unsigned int& pt) {
  asm volatile(
      "global_load_dwordx4 %0, %4, off sc0 sc1\n\t"
      "global_load_dwordx4 %1, %5, off sc0 sc1\n\t"
      "global_load_dwordx4 %2, %6, off sc0 sc1\n\t"
      "global_load_dword %3, %7, off sc0 sc1\n\t"
      "s_waitcnt vmcnt(0)"
      : "=&v"(r0), "=&v"(r1), "=&v"(r2), "=&v"(pt)
      : "v"(p0), "v"(p1), "v"(p2), "v"(pp)
      : "memory");
}

// ---------------- convert f32 weights -> bf16 (Whh0, Wih1, Whh1, Wout) ----------------
__global__ __launch_bounds__(256) void k_cvt(const float* __restrict__ s0, const float* __restrict__ s1,
                                             const float* __restrict__ s2, const float* __restrict__ s3,
                                             unsigned short* __restrict__ d0, unsigned short* __restrict__ d1,
                                             unsigned short* __restrict__ d2, unsigned short* __restrict__ d3) {
  int j = blockIdx.x * 256 + threadIdx.x;   // 6656*256 = 1,703,936 vec8 jobs exactly
  const float* s; unsigned short* d; int o;
  if (j < 524288)       { s = s0; d = d0; o = j; }
  else if (j < 1048576) { s = s1; d = d1; o = j - 524288; }
  else if (j < 1572864) { s = s2; d = d2; o = j - 1048576; }
  else                  { s = s3; d = d3; o = j - 1572864; }
  size_t off = (size_t)o * 8;
  f32x4 v0 = *(const f32x4*)(s + off);
  f32x4 v1 = *(const f32x4*)(s + off + 4);
  bf16x8 r;
#pragma unroll
  for (int k = 0; k < 4; k++) { r[k] = (short)f2bf(v0[k]); r[4 + k] = (short)f2bf(v1[k]); }
  *(bf16x8*)(d + off) = r;
}

// ---------------- prep: embedding gather (f32) + zero BOTH parities of exchange -------
__global__ __launch_bounds__(256) void k_prep(const int* __restrict__ ys,
                                              const float* __restrict__ embed,
                                              float* __restrict__ eys,
                                              unsigned int* __restrict__ exch) {
  int idx = blockIdx.x * 256 + threadIdx.x;   // 16384 threads
  int row = idx >> 6;
  int e = (idx & 63) * 8;
  int y = ys[row];
  f32x4 v0 = {0.f, 0.f, 0.f, 0.f}, v1 = {0.f, 0.f, 0.f, 0.f};
  if (y != 0) {
    v0 = *(const f32x4*)(embed + (size_t)y * 512 + e);
    v1 = *(const f32x4*)(embed + (size_t)y * 512 + e + 4);
  }
  *(f32x4*)(eys + (size_t)row * 512 + e) = v0;
  *(f32x4*)(eys + (size_t)row * 512 + e + 4) = v1;
  exch[idx] = 0u;                 // 32768 dwords: h0[2][8192] + h1[2][8192]
  exch[idx + 16384] = 0u;
}

// -------- generic small GEMM: C = A(f32 MxK) @ W(f32 NxK)^T + b1 + b2; C f32 or bf16 ----
__global__ __launch_bounds__(256) void k_gemm_bias(const float* __restrict__ A,
                                                   const float* __restrict__ W,
                                                   const float* __restrict__ b1,
                                                   const float* __restrict__ b2,
                                                   void* __restrict__ Cout, int obf,
                                                   int M, int N, int K) {
  __shared__ unsigned short Als[64][40];
  __shared__ unsigned short Wls[64][40];
  int tid = threadIdx.x;
  int lane = tid & 63, wid = tid >> 6;
  int mtiles = M >> 6;
  int mt = blockIdx.x % mtiles, nt = blockIdx.x / mtiles;
  int srow = tid >> 2, sseg = tid & 3;
  f32x4 acc[4];
#pragma unroll
  for (int nf = 0; nf < 4; nf++) acc[nf] = (f32x4){0.f, 0.f, 0.f, 0.f};

  for (int kc = 0; kc < K; kc += 32) {
    const float* ap = A + (size_t)(mt * 64 + srow) * K + kc + sseg * 8;
    const float* wp = W + (size_t)(nt * 64 + srow) * K + kc + sseg * 8;
    f32x4 a0 = *(const f32x4*)ap, a1 = *(const f32x4*)(ap + 4);
    f32x4 w0 = *(const f32x4*)wp, w1 = *(const f32x4*)(wp + 4);
    bf16x8 av, wv;
#pragma unroll
    for (int k = 0; k < 4; k++) {
      av[k] = (short)f2bf(a0[k]); av[4 + k] = (short)f2bf(a1[k]);
      wv[k] = (short)f2bf(w0[k]); wv[4 + k] = (short)f2bf(w1[k]);
    }
    __syncthreads();
    *(bf16x8*)(&Als[srow][sseg * 8]) = av;
    *(bf16x8*)(&Wls[srow][sseg * 8]) = wv;
    __syncthreads();
    bf16x8 af = *(const bf16x8*)(&Als[wid * 16 + (lane & 15)][(lane >> 4) * 8]);
#pragma unroll
    for (int nf = 0; nf < 4; nf++) {
      bf16x8 bf = *(const bf16x8*)(&Wls[nf * 16 + (lane & 15)][(lane >> 4) * 8]);
      acc[nf] = __builtin_amdgcn_mfma_f32_16x16x32_bf16(af, bf, acc[nf], 0, 0, 0);
    }
  }
  int rloc = (lane >> 4) * 4;
  int col0 = lane & 15;
#pragma unroll
  for (int nf = 0; nf < 4; nf++) {
    int n = nt * 64 + nf * 16 + col0;
    float bias = 0.f;
    if (b1) bias += b1[n];
    if (b2) bias += b2[n];
#pragma unroll
    for (int r = 0; r < 4; r++) {
      int m = mt * 64 + wid * 16 + rloc + r;
      float v = acc[nf][r] + bias;
      if (obf) ((unsigned short*)Cout)[(size_t)m * N + n] = f2bf(v);
      else     ((float*)Cout)[(size_t)m * N + n] = v;
    }
  }
}

// ---------------- fused LSTM v5: split L0/L1 blocks, decoupled chains -----------------
// 128 blocks x 512 threads. bid<64: layer0 block (16 ch); bid>=64: layer1 block (16 ch).
// Exchange record: 16B = {3 x f32, u32 tag}, single dwordx4 sc0 sc1 store. Parity dbuf.
// L0 round p (0..63): spin h0[p] tags == p AND probe h1 tags >= p-1 (progress proof for
// safe parity reuse; monotone >=) -> stage -> bar -> MFMA -> red -> bar -> gates(+X0
// prefetched) -> export h0[p+1]. L1 round p (1..64): spin h0[p] & h1[p-1] exact ->
// stage both -> bar -> MFMA K=2048 -> red -> bar -> gates(+bias) -> hdec + export h1[p].
__global__ __launch_bounds__(512) void k_lstm_fused(
    const float* __restrict__ X0,            // (B,U,4096)
    float* __restrict__ hdec,                // (B,U,1024) f32
    const unsigned short* __restrict__ W_hh0,
    const unsigned short* __restrict__ W_ih1,
    const unsigned short* __restrict__ W_hh1,
    const float* __restrict__ b_ih1,
    const float* __restrict__ b_hh1,
    unsigned int* __restrict__ exch) {       // h0:[2][8192]dw, h1:+16384:[2][8192]dw
  __shared__ unsigned short X_lds[4][2064];
  __shared__ float red[8][4][16][4];
  int tid = threadIdx.x;
  int lane = tid & 63, w = tid >> 6;
  bool isL1 = blockIdx.x >= 64;
  int bidl = blockIdx.x & 63;
  int base = bidl * 16;
  unsigned int* REC0 = exch;
  unsigned int* REC1 = exch + 16384;

  // ---- preload weight B-frags (same fragment scheme as r8-r13 passing kernels) ----
  bf16x8 wf[4][8];                           // L0 uses [.][0..3]
  int ch = lane & 15;
  int klo = (lane >> 4) << 3;
  int kb = isL1 ? w * 256 : w * 128;
#pragma unroll
  for (int nt = 0; nt < 4; nt++) {
    int grow = nt * 1024 + base + ch;
    if (!isL1) {
#pragma unroll
      for (int ks = 0; ks < 4; ks++)
        wf[nt][ks] = *(const bf16x8*)(W_hh0 + (size_t)grow * 1024 + kb + ks * 32 + klo);
    } else {
#pragma unroll
      for (int ks = 0; ks < 8; ks++) {
        int k = kb + ks * 32 + klo;
        const unsigned short* src = (k < 1024) ? (W_ih1 + (size_t)grow * 1024 + k)
                                               : (W_hh1 + (size_t)grow * 1024 + (k - 1024));
        wf[nt][ks] = *(const bf16x8*)src;
      }
    }
  }

  // gate-thread state (tid<64): gch = tid>>2, gb = tid&3
  float creg = 0.f;
  float bs0 = 0.f, bs1 = 0.f, bs2 = 0.f, bs3 = 0.f;
  int gch = tid >> 2, gb = tid & 3;
  if (isL1 && tid < 64) {
    int c = base + gch;
    bs0 = b_ih1[c] + b_hh1[c];
    bs1 = b_ih1[1024 + c] + b_hh1[1024 + c];
    bs2 = b_ih1[2048 + c] + b_hh1[2048 + c];
    bs3 = b_ih1[3072 + c] + b_hh1[3072 + c];
  }

  // consumer unit slots: 1408 units per layer-step, 3 slots per thread
  int uoff[3], upb[3], us[3]; bool uneed[3];
#pragma unroll
  for (int r = 0; r < 3; r++) {
    int u = tid + r * 512;
    uneed[r] = (u < 1408);
    int uc = uneed[r] ? u : 1407;
    int pb = uc / 22;
    int s = uc - pb * 22;
    upb[r] = pb; us[r] = s;
    uoff[r] = pb * 128 + s * 4;
  }

#define STAGE_UNIT(rv, rr, off1024)                                           \
  if (uneed[rv]) {                                                            \
    int pb_ = upb[rv], s_ = us[rv];                                           \
    _Pragma("unroll")                                                         \
    for (int j_ = 0; j_ < 3; j_++) {                                          \
      int i_ = 3 * s_ + j_;                                                   \
      if (i_ < 64) {                                                          \
        union { unsigned int u; float f; } cv_; cv_.u = rr[j_];               \
        X_lds[i_ & 3][off1024 + pb_ * 16 + (i_ >> 2)] = f2bf(cv_.f);          \
      }                                                                       \
    }                                                                         \
  }

  int ar = ch & 3;
  if (!isL1) {
    // =================== LAYER 0 BLOCK: rounds 0..63 ===================
    for (int p = 0; p < 64; p++) {
      // X0 prefetch (issued before spin; consumed after reduce)
      float xp0 = 0.f, xp1 = 0.f, xp2 = 0.f, xp3 = 0.f;
      if (tid < 64) {
        const float* x0p = X0 + ((size_t)(gb * 64 + p)) * 4096 + base + gch;
        xp0 = x0p[0]; xp1 = x0p[1024]; xp2 = x0p[2048]; xp3 = x0p[3072];
      }
      // spin: own h0[p] records + h1 progress probe (>= p-1)
      {
        unsigned int* b0 = REC0 + (unsigned)(p & 1) * 8192;
        const unsigned int* pp = REC1 + (unsigned)((p - 1) & 1) * 8192 + (tid & 63) * 128 + 3;
        unsigned expP = (p == 0) ? 0u : (unsigned)(p - 1);
        u32x4 r0, r1, r2; unsigned int pt;
        while (true) {
          spin_load3p(b0 + uoff[0], b0 + uoff[1], b0 + uoff[2], pp, r0, r1, r2, pt);
          bool ok = (!uneed[0] || r0[3] == (unsigned)p) && (!uneed[1] || r1[3] == (unsigned)p) &&
                    (!uneed[2] || r2[3] == (unsigned)p) && (pt >= expP);
          if (ok) break;
          __builtin_amdgcn_s_sleep(1);
        }
        STAGE_UNIT(0, r0, 0) STAGE_UNIT(1, r1, 0) STAGE_UNIT(2, r2, 0)
      }
      __syncthreads();
      // MFMA: 4 ks x 4 gates over this wave's K=128
      {
        f32x4 acc[4];
#pragma unroll
        for (int nt = 0; nt < 4; nt++) acc[nt] = (f32x4){0.f, 0.f, 0.f, 0.f};
#pragma unroll
        for (int ks = 0; ks < 4; ks++) {
          bf16x8 a = *(const bf16x8*)&X_lds[ar][kb + ks * 32 + klo];
#pragma unroll
          for (int nt = 0; nt < 4; nt++)
            acc[nt] = __builtin_amdgcn_mfma_f32_16x16x32_bf16(a, wf[nt][ks], acc[nt], 0, 0, 0);
        }
        if (lane < 16) {
#pragma unroll
          for (int nt = 0; nt < 4; nt++) *(f32x4*)&red[w][nt][lane][0] = acc[nt];
        }
      }
      __syncthreads();
      // gates: direct 8-partial sum + X0 + nonlin + export h0[p+1]
      if (tid < 64) {
        float g0 = 0.f, g1 = 0.f, g2 = 0.f, g3 = 0.f;
#pragma unroll
        for (int w8 = 0; w8 < 8; w8++) {
          g0 += red[w8][0][gch][gb]; g1 += red[w8][1][gch][gb];
          g2 += red[w8][2][gch][gb]; g3 += red[w8][3][gch][gb];
        }
        g0 += xp0; g1 += xp1; g2 += xp2; g3 += xp3;
        float ii = 1.f / (1.f + __expf(-g0));
        float ff = 1.f / (1.f + __expf(-g1));
        float oo = 1.f / (1.f + __expf(-g3));
        float cn = ff * creg + ii * tanhf(g2);
        creg = cn;
        float hn = oo * tanhf(cn);
        int l = tid;
        float v0 = __shfl(hn, 3 * l);
        float v1 = __shfl(hn, 3 * l + 1);
        float v2 = __shfl(hn, 3 * l + 2);
        if (l < 22) {
          unsigned tag = (unsigned)(p + 1);
          unsigned int* rec = REC0 + (tag & 1) * 8192 + bidl * 128 + l * 4;
          u32x4 d;
          d[0] = __float_as_uint(v0); d[1] = __float_as_uint(v1);
          d[2] = __float_as_uint(v2); d[3] = tag;
          store16_coh(rec, d);
        }
      }
    }
  } else {
    // =================== LAYER 1 BLOCK: rounds 1..64 ===================
    for (int p = 1; p <= 64; p++) {
      // spin: h0[p] exact + h1[p-1] exact
      {
        unsigned int* b0 = REC0 + (unsigned)(p & 1) * 8192;
        unsigned int* b1 = REC1 + (unsigned)((p - 1) & 1) * 8192;
        u32x4 r0, r1, r2, r3, r4, r5;
        unsigned exp0 = (unsigned)p, exp1 = (unsigned)(p - 1);
        while (true) {
          spin_load6(b0 + uoff[0], b0 + uoff[1], b0 + uoff[2],
                     b1 + uoff[0], b1 + uoff[1], b1 + uoff[2],
                     r0, r1, r2, r3, r4, r5);
          bool ok = (!uneed[0] || (r0[3] == exp0 && r3[3] == exp1)) &&
                    (!uneed[1] || (r1[3] == exp0 && r4[3] == exp1)) &&
                    (!uneed[2] || (r2[3] == exp0 && r5[3] == exp1));
          if (ok) break;
          __builtin_amdgcn_s_sleep(1);
        }
        STAGE_UNIT(0, r0, 0) STAGE_UNIT(1, r1, 0) STAGE_UNIT(2, r2, 0)
        STAGE_UNIT(0, r3, 1024) STAGE_UNIT(1, r4, 1024) STAGE_UNIT(2, r5, 1024)
      }
      __syncthreads();
      // MFMA: 8 ks x 4 gates over this wave's K=256 of [h0|h1]
      {
        f32x4 acc[4];
#pragma unroll
        for (int nt = 0; nt < 4; nt++) acc[nt] = (f32x4){0.f, 0.f, 0.f, 0.f};
#pragma unroll
        for (int ks = 0; ks < 8; ks++) {
          bf16x8 a = *(const bf16x8*)&X_lds[ar][kb + ks * 32 + klo];
#pragma unroll
          for (int nt = 0; nt < 4; nt++)
            acc[nt] = __builtin_amdgcn_mfma_f32_16x16x32_bf16(a, wf[nt][ks], acc[nt], 0, 0, 0);
        }
        if (lane < 16) {
#pragma unroll
          for (int nt = 0; nt < 4; nt++) *(f32x4*)&red[w][nt][lane][0] = acc[nt];
        }
      }
      __syncthreads();
      // gates: direct sum + bias + nonlin + hdec + export h1[p]
      if (tid < 64) {
        float g0 = 0.f, g1 = 0.f, g2 = 0.f, g3 = 0.f;
#pragma unroll
        for (int w8 = 0; w8 < 8; w8++) {
          g0 += red[w8][0][gch][gb]; g1 += red[w8][1][gch][gb];
          g2 += red[w8][2][gch][gb]; g3 += red[w8][3][gch][gb];
        }
        g0 += bs0; g1 += bs1; g2 += bs2; g3 += bs3;
        float ii = 1.f / (1.f + __expf(-g0));
        float ff = 1.f / (1.f + __expf(-g1));
        float oo = 1.f / (1.f + __expf(-g3));
        float cn = ff * creg + ii * tanhf(g2);
        creg = cn;
        float hn = oo * tanhf(cn);
        hdec[((size_t)(gb * 64 + (p - 1))) * 1024 + base + gch] = hn;
        int l = tid;
        float v0 = __shfl(hn, 3 * l);
        float v1 = __shfl(hn, 3 * l + 1);
        float v2 = __shfl(hn, 3 * l + 2);
        if (l < 22) {
          unsigned tag = (unsigned)p;
          unsigned int* rec = REC1 + (tag & 1) * 8192 + bidl * 128 + l * 4;
          u32x4 d;
          d[0] = __float_as_uint(v0); d[1] = __float_as_uint(v1);
          d[2] = __float_as_uint(v2); d[3] = tag;
          store16_coh(rec, d);
        }
      }
    }
  }
#undef STAGE_UNIT
}

// ---------------- k_z: Z[m][k] = tanh(encp[b,t,k] + decp[b,u,k]) as bf16 --------------
__global__ __launch_bounds__(256) void k_z(const unsigned short* __restrict__ encpb, // (512,512) bf16
                                           const unsigned short* __restrict__ decpb, // (256,512) bf16
                                           unsigned short* __restrict__ Z) {
  int idx = blockIdx.x * 256 + threadIdx.x;   // 2,097,152 jobs (8192 blocks)
  int m = idx >> 6;
  int k0 = (idx & 63) * 8;
  int bt = m >> 6;                            // b*128+t
  int b = m >> 13, u = m & 63;
  bf16x8 ev = *(const bf16x8*)(encpb + (size_t)bt * 512 + k0);
  bf16x8 dv = *(const bf16x8*)(decpb + (size_t)(b * 64 + u) * 512 + k0);
  bf16x8 r;
#pragma unroll
  for (int j = 0; j < 8; j++) {
    float x = bfu2f((unsigned short)ev[j]) + bfu2f((unsigned short)dv[j]);
    float e = __expf(x + x);
    r[j] = (short)f2bf(1.f - 2.f / (e + 1.f));
  }
  *(bf16x8*)(Z + (size_t)m * 512 + k0) = r;
}

// ---------------- k_gemm_out: out = Z @ Wout^T + bout, Wout slice LDS-resident --------
__global__ __launch_bounds__(512, 2) void k_gemm_out(const unsigned short* __restrict__ Z,    // (32768,512) bf16
                                                     const unsigned short* __restrict__ Wout, // (2048,512) bf16
                                                     const float* __restrict__ bout,          // (2048) f32
                                                     float* __restrict__ out) {               // (32768,2048) f32
  __shared__ unsigned short Wls[8][8192];   // 8 k-chunks x (128 n-rows x 64 k, swizzled)
  int tid = threadIdx.x;
  int lane = tid & 63, wid = tid >> 6;
  int bid = blockIdx.x;
  int mpart = bid & 15, ngroup = bid >> 4;

#pragma unroll
  for (int kc = 0; kc < 8; kc++) {
    unsigned short* dst = &Wls[kc][0];
#pragma unroll
    for (int q = 0; q < 2; q++) {
      int idx = tid + q * 512;
      int n = idx >> 3, sl = idx & 7;
      int ss = sl ^ (n & 7);
      gload_lds16(Wout + (size_t)(ngroup * 128 + n) * 512 + kc * 64 + ss * 8, dst + idx * 8);
    }
  }
  float bb[8];
#pragma unroll
  for (int nf = 0; nf < 8; nf++) bb[nf] = bout[ngroup * 128 + nf * 16 + (lane & 15)];
  asm volatile("s_waitcnt vmcnt(0)" ::: "memory");
  __syncthreads();

  int rowwave = mpart * 2048 + wid * 256;
  int ocol0 = ngroup * 128;
  for (int mg = 0; mg < 4; mg++) {
    int rowbase = rowwave + mg * 64;
    f32x4 acc[4][8];
#pragma unroll
    for (int mf = 0; mf < 4; mf++)
#pragma unroll
      for (int nf = 0; nf < 8; nf++) acc[mf][nf] = (f32x4){0.f, 0.f, 0.f, 0.f};

#pragma unroll
    for (int ks = 0; ks < 16; ks++) {
      bf16x8 a[4];
#pragma unroll
      for (int mf = 0; mf < 4; mf++) {
        int r = rowbase + mf * 16 + (lane & 15);
        a[mf] = *(const bf16x8*)(Z + (size_t)r * 512 + ks * 32 + ((lane >> 4) << 3));
      }
      const unsigned short* Wb = &Wls[ks >> 1][0];
      int slot = (ks & 1) * 4 + (lane >> 4);
#pragma unroll
      for (int nf = 0; nf < 8; nf++) {
        int nl = nf * 16 + (lane & 15);
        int phys = slot ^ (nl & 7);
        bf16x8 bfr = *(const bf16x8*)(Wb + nl * 64 + phys * 8);
#pragma unroll
        for (int mf = 0; mf < 4; mf++)
          acc[mf][nf] = __builtin_amdgcn_mfma_f32_16x16x32_bf16(a[mf], bfr, acc[mf][nf], 0, 0, 0);
      }
    }
#pragma unroll
    for (int mf = 0; mf < 4; mf++) {
      int rb = rowbase + mf * 16 + ((lane >> 4) << 2);
#pragma unroll
      for (int nf = 0; nf < 8; nf++) {
        int o = ocol0 + nf * 16 + (lane & 15);
        float bias = bb[nf];
#pragma unroll
        for (int q = 0; q < 4; q++)
          __builtin_nontemporal_store(acc[mf][nf][q] + bias, &out[(size_t)(rb + q) * 2048 + o]);
      }
    }
  }
}

// ---------------- launch ----------------
extern "C" void kernel_launch(void* const* d_in, const int* in_sizes, int n_in,
                              void* d_out, int out_size, void* d_ws, size_t ws_size,
                              hipStream_t stream) {
  const float* hs   = (const float*)d_in[0];
  const int*   ys   = (const int*)d_in[1];
  const float* emb  = (const float*)d_in[2];
  const float* Wih0 = (const float*)d_in[3];
  const float* Whh0 = (const float*)d_in[4];
  const float* bih0 = (const float*)d_in[5];
  const float* bhh0 = (const float*)d_in[6];
  const float* Wih1 = (const float*)d_in[7];
  const float* Whh1 = (const float*)d_in[8];
  const float* bih1 = (const float*)d_in[9];
  const float* bhh1 = (const float*)d_in[10];
  const float* Wenc = (const float*)d_in[11];
  const float* benc = (const float*)d_in[12];
  const float* Wdec = (const float*)d_in[13];
  const float* Wout = (const float*)d_in[14];
  const float* bout = (const float*)d_in[15];

  // Workspace map (liveness-overlapped):
  //  [0,        2,097,152)  Woutb  bf16
  //  [2,097,152 2,621,440)  encpb  bf16
  //  [2,621,440 2,883,584)  decpb  bf16
  //  [2,883,584 3,014,656)  exch   u32 32768 dw = 128KB (dedicated)
  //  [3,031,040 ...)        Z      bf16; overlays (dead before k_z):
  //     eys, X0, hdec, Whh0b, Wih1b, Whh1b
  char* ws = (char*)d_ws;
  unsigned short* Woutb = (unsigned short*)(ws + 0);
  unsigned short* encpb = (unsigned short*)(ws + 2097152);
  unsigned short* decpb = (unsigned short*)(ws + 2621440);
  unsigned int*   exch  = (unsigned int*)(ws + 2883584);
  unsigned short* Z     = (unsigned short*)(ws + 3031040);
  float*          eys   = (float*)(ws + 3031040);            //   524,288
  float*          X0    = (float*)(ws + 3555328);            // 4,194,304
  float*          hdec  = (float*)(ws + 7749632);            // 1,048,576
  unsigned short* Whh0b = (unsigned short*)(ws + 8798208);   // 8,388,608
  unsigned short* Wih1b = (unsigned short*)(ws + 17186816);  // 8,388,608
  unsigned short* Whh1b = (unsigned short*)(ws + 25575424);  // 8,388,608 -> 33,964,032
  float*          out   = (float*)d_out;

  k_cvt<<<6656, 256, 0, stream>>>(Whh0, Wih1, Whh1, Wout, Whh0b, Wih1b, Whh1b, Woutb);
  k_prep<<<64, 256, 0, stream>>>(ys, emb, eys, exch);
  // X0 = eys @ Wih0^T + bih0 + bhh0   (f32 out; M=256, N=4096, K=512)
  k_gemm_bias<<<256, 256, 0, stream>>>(eys, Wih0, bih0, bhh0, X0, 0, 256, 4096, 512);
  // encpb = bf16(hs @ Wenc^T + benc)  (M=512, N=512, K=512)
  k_gemm_bias<<<64, 256, 0, stream>>>(hs, Wenc, benc, nullptr, encpb, 1, 512, 512, 512);
  // fused LSTM v5: split-layer blocks, decoupled chains
  k_lstm_fused<<<128, 512, 0, stream>>>(X0, hdec, Whh0b, Wih1b, Whh1b, bih1, bhh1, exch);
  // decpb = bf16(hdec @ Wdec^T)       (M=256, N=512, K=1024)
  k_gemm_bias<<<32, 256, 0, stream>>>(hdec, Wdec, nullptr, nullptr, decpb, 1, 256, 512, 1024);
  // Z = tanh(enc + dec) materialized bf16
  k_z<<<8192, 256, 0, stream>>>(encpb, decpb, Z);
  // out = Z @ Wout^T + bout (Wout slice LDS-resident per block)
  k_gemm_out<<<256, 512, 0, stream>>>(Z, Woutb, bout, out);
}